// Round 15
// baseline (322.645 us; speedup 1.0000x reference)
//
#include <hip/hip_runtime.h>
#include <hip/hip_bf16.h>
#include <stdint.h>

// ---------------- problem constants (fixed by setup_inputs) ----------------
#define NHD   12        // heads
#define NPT   4         // points
#define CDIM  768
#define HDIM  64
#define NLVL  3
#define LQ    4096
#define NB    4
#define LIN   21504     // 128*128 + 64*64 + 32*32
#define MQ    (NB*LQ)   // 16384 query rows
#define MF    (NB*LIN)  // 86016 feat rows
#define CAT_N 512       // fused so(288) | aw(144 real + pad)
#define AW_OFF 288
#define WSCL  16.f      // so/aw weight pre-scale (fp8 denormal avoidance)

typedef float  f32x4  __attribute__((ext_vector_type(4)));
typedef float  f32x2  __attribute__((ext_vector_type(2)));
typedef float  f32x16 __attribute__((ext_vector_type(16)));
typedef int    i32x8  __attribute__((ext_vector_type(8)));

__device__ __forceinline__ i32x8 mk8(uint4 lo, uint4 hi) {
  i32x8 v;
  v[0] = (int)lo.x; v[1] = (int)lo.y; v[2] = (int)lo.z; v[3] = (int)lo.w;
  v[4] = (int)hi.x; v[5] = (int)hi.y; v[6] = (int)hi.z; v[7] = (int)hi.w;
  return v;
}

// ------- merged weight prep: 4 transposes (fp8) + cat bias, 1 launch -------
// blocks [0,576): vp_w -> vp_w8 ; [576,1152): op_w -> op_w8 ;
// [1152,1368): so_w -> cat_w8 rows 0..287 (x16) ;
// [1368,1536): aw_w -> cat_w8 rows 288..511 (x16, zero-pad n>=144) ;
// block 1536: cat bias pack.
__global__ __launch_bounds__(256) void prep_weights(
    const float* __restrict__ vp_w, const float* __restrict__ op_w,
    const float* __restrict__ so_w, const float* __restrict__ aw_w,
    const float* __restrict__ so_b, const float* __restrict__ aw_b,
    char* __restrict__ vp_w8, char* __restrict__ op_w8,
    char* __restrict__ cat_w8, float* __restrict__ cat_bp)
{
  const int b = blockIdx.x;
  if (b == 1536) {
    const int i = threadIdx.x;
#pragma unroll
    for (int it = 0; it < 2; ++it) {
      const int idx = i + it * 256;
      float v = 0.f;
      if (idx < 288) v = so_b[idx];
      else if (idx < 432) v = aw_b[idx - AW_OFF];
      cat_bp[idx] = v;
    }
    return;
  }
  const float* W; char* Wt; int Nsrc, rowoff; float scale;
  int lb;
  if (b < 576)       { W = vp_w; Wt = vp_w8;  Nsrc = 768; rowoff = 0;   scale = 1.f;  lb = b; }
  else if (b < 1152) { W = op_w; Wt = op_w8;  Nsrc = 768; rowoff = 0;   scale = 1.f;  lb = b - 576; }
  else if (b < 1368) { W = so_w; Wt = cat_w8; Nsrc = 288; rowoff = 0;   scale = WSCL; lb = b - 1152; }
  else               { W = aw_w; Wt = cat_w8; Nsrc = 144; rowoff = 288; scale = WSCL; lb = b - 1368; }

  __shared__ float t[32][33];
  const int k0 = (lb % 24) * 32;
  const int n0 = (lb / 24) * 32;
  const int tx = threadIdx.x & 31, ty = threadIdx.x >> 5;
#pragma unroll
  for (int i = ty; i < 32; i += 8) {
    const int n = n0 + tx;
    t[i][tx] = (n < Nsrc) ? W[(size_t)(k0 + i) * Nsrc + n] * scale : 0.f;
  }
  __syncthreads();
#pragma unroll
  for (int i = ty; i < 32; i += 8) {
    const int n = rowoff + n0 + i;
    uint32_t pk = __builtin_amdgcn_cvt_pk_fp8_f32(t[tx][i], 0.f, 0, false);
    Wt[(size_t)n * CDIM + k0 + tx] = (char)(pk & 0xff);
  }
}

// ---------------- LayerNorm, 1 wave/row, fp8 e4m3 out ----------------------
__global__ __launch_bounds__(256) void ln_wave(const float* __restrict__ x,
                                               const float* __restrict__ w,
                                               const float* __restrict__ b,
                                               char* __restrict__ y) {
  const int row  = blockIdx.x * 4 + (threadIdx.x >> 6);
  const int lane = threadIdx.x & 63;
  const float4* xr = (const float4*)(x + (size_t)row * CDIM);
  float4 v[3];
  v[0] = xr[lane]; v[1] = xr[lane + 64]; v[2] = xr[lane + 128];
  float s1 = 0.f, s2 = 0.f;
#pragma unroll
  for (int i = 0; i < 3; ++i) {
    s1 += v[i].x + v[i].y + v[i].z + v[i].w;
    s2 += v[i].x*v[i].x + v[i].y*v[i].y + v[i].z*v[i].z + v[i].w*v[i].w;
  }
#pragma unroll
  for (int o = 32; o > 0; o >>= 1) { s1 += __shfl_xor(s1, o); s2 += __shfl_xor(s2, o); }
  const float mu = s1 * (1.f / CDIM);
  const float rs = rsqrtf(s2 * (1.f / CDIM) - mu * mu + 1e-6f);
#pragma unroll
  for (int i = 0; i < 3; ++i) {
    const float4 w4 = ((const float4*)w)[lane + i * 64];
    const float4 b4 = ((const float4*)b)[lane + i * 64];
    const float o0 = (v[i].x - mu) * rs * w4.x + b4.x;
    const float o1 = (v[i].y - mu) * rs * w4.y + b4.y;
    const float o2 = (v[i].z - mu) * rs * w4.z + b4.z;
    const float o3 = (v[i].w - mu) * rs * w4.w + b4.w;
    uint32_t pk = 0;
    pk = __builtin_amdgcn_cvt_pk_fp8_f32(o0, o1, pk, false);
    pk = __builtin_amdgcn_cvt_pk_fp8_f32(o2, o3, pk, true);
    ((uint32_t*)(y + (size_t)row * CDIM))[lane + i * 64] = pk;
  }
}

// ======== 128x128 MX fp8 GEMM: A via LDS (3-buf), B direct from L2 =========
// C = A[M][K](e4m3) * Wt[N][K](e4m3)^T. Unity e8m0 scales (0x7F) = exact fp8.
// 256 thr = 4 waves (2M x 2N), per-wave 64x64 = 2x2 of 32x32.
// A: 3 LDS bufs x 8 KB (rows [128][64B], chunk swizzle p^(r&3)); stage tile
// t+2 during t; ONLY manual wait = prologue vmcnt(2) (tile 0 landed).
// B: per-lane global loads (2 x dwordx4 per fragment) -- weights are L2-hot
// (<=590 KB); B loads are register deps so the COMPILER inserts the correct
// vmcnt before each MFMA (drains B(t)+A(t+1), leaves A(t+2) in flight when
// issue order holds). Halves LDS reads & writes vs B-in-LDS (R14).
// Operand frag: lane l = row (l&31), k = (l>>5)*32 + e. C/D (verified R11):
// col = lane&31, row = (reg&3)+8*(reg>>2)+4*(lane>>5).
// MODE 0: fp8 head-major value store [n*NHD+head][LIN][64].
// MODE 1: f32 row-major, out = acc*oscale + bias.
// MODE 2: f32 row-major, out = resid + gamma*(acc+bias).
template<int MODE>
__global__ __launch_bounds__(256, 3) void gemm_mx(
    const char* __restrict__ A, const char* __restrict__ Wt,
    const float* __restrict__ bias, void* __restrict__ Cout,
    int M, int N, int K, int nTN, float oscale,
    const float* __restrict__ resid, const float* __restrict__ gammav)
{
  __shared__ __align__(16) char lds[36864];   // 3 x 8 KiB bufs + epilogue ovl

  int bid = blockIdx.x;
  const int nwg = gridDim.x;
  if ((nwg & 7) == 0) {                 // XCD-chunked swizzle (bijective)
    const int chunk = nwg >> 3;
    bid = (bid & 7) * chunk + (bid >> 3);
  }
  const int mt = bid / nTN, ntl = bid - mt * nTN;
  const int m0 = mt * 128, n0 = ntl * 128;
  const int tid  = threadIdx.x;
  const int lane = tid & 63, wid = tid >> 6;
  const int wm = wid >> 1, wn = wid & 1;          // 2x2 wave grid
  const int lr31 = lane & 31, lkb = lane >> 5;

  f32x16 acc[2][2] = {};

  // stage A half of tile kt into buf (2 x 16B gload_lds per thread)
  auto stageA = [&](int kt, int buf) {
    const int k0 = kt * 64;
    char* dst0 = lds + buf * 8192;
#pragma unroll
    for (int it = 0; it < 2; ++it) {
      const int i = it * 256 + tid;              // chunk 0..511
      const int r = i >> 2, p = i & 3;
      const int c = p ^ (r & 3);                 // source chunk (involution)
      const char* src = A + (size_t)(m0 + r) * K + k0 + c * 16;
      char* dst = dst0 + (it * 256 + wid * 64) * 16;   // + lane*16 by HW
      __builtin_amdgcn_global_load_lds(
          (const __attribute__((address_space(1))) uint32_t*)src,
          (__attribute__((address_space(3))) uint32_t*)dst, 16, 0, 0);
    }
  };
  auto rdA = [&](int buf, int row) -> i32x8 {
    const char* base = lds + buf * 8192 + row * 64;
    const int s = row & 3;
    const uint4 lo = *(const uint4*)(base + ((2 * lkb)     ^ s) * 16);
    const uint4 hi = *(const uint4*)(base + ((2 * lkb + 1) ^ s) * 16);
    return mk8(lo, hi);
  };
  // B fragment straight from global (L2-resident weights), no swizzle
  auto rdB = [&](int kt, int nt2) -> i32x8 {
    const char* p = Wt + (size_t)(n0 + wn * 64 + nt2 * 32 + lr31) * K
                       + kt * 64 + lkb * 32;
    const uint4 lo = *(const uint4*)p;
    const uint4 hi = *(const uint4*)(p + 16);
    return mk8(lo, hi);
  };

  const int nk = K >> 6;                          // 12 K-tiles
  // prologue: stage A tiles 0,1 (4 insts outstanding); tile 0 landed at <=2
  stageA(0, 0); stageA(1, 1);
  asm volatile("s_waitcnt vmcnt(2)" ::: "memory");
  __builtin_amdgcn_s_barrier();
  asm volatile("" ::: "memory");

  for (int t = 0; t < nk; ++t) {
    const int cur = t % 3;
    const i32x8 b0 = rdB(t, 0);                  // issue B first (L2 latency)
    const i32x8 b1 = rdB(t, 1);
    const i32x8 a0 = rdA(cur, wm * 64 + lr31);
    const i32x8 a1 = rdA(cur, wm * 64 + 32 + lr31);
    if (t + 2 < nk) stageA(t + 2, (t + 2) % 3);
    __builtin_amdgcn_s_setprio(1);
    acc[0][0] = __builtin_amdgcn_mfma_scale_f32_32x32x64_f8f6f4(
        a0, b0, acc[0][0], 0, 0, 0, 0x7F7F7F7F, 0, 0x7F7F7F7F);
    acc[0][1] = __builtin_amdgcn_mfma_scale_f32_32x32x64_f8f6f4(
        a0, b1, acc[0][1], 0, 0, 0, 0x7F7F7F7F, 0, 0x7F7F7F7F);
    acc[1][0] = __builtin_amdgcn_mfma_scale_f32_32x32x64_f8f6f4(
        a1, b0, acc[1][0], 0, 0, 0, 0x7F7F7F7F, 0, 0x7F7F7F7F);
    acc[1][1] = __builtin_amdgcn_mfma_scale_f32_32x32x64_f8f6f4(
        a1, b1, acc[1][1], 0, 0, 0, 0x7F7F7F7F, 0, 0x7F7F7F7F);
    __builtin_amdgcn_s_setprio(0);
    __builtin_amdgcn_s_barrier();                // A(t+1) visible next iter
    asm volatile("" ::: "memory");
  }

  // ---- epilogue ----
  if constexpr (MODE == 0) {
    // fp8 head-major value store via per-wave LDS staging ([32][68] f32)
    const int head  = (n0 + wn * 64) >> 6;
    const int n_img = (unsigned)m0 / LIN;         // LIN%128==0: no crossing
    char* plane = (char*)Cout + ((size_t)(n_img * NHD + head) * LIN
                                 + (m0 - n_img * LIN)) * 64;
    float bcol[2];
#pragma unroll
    for (int nt2 = 0; nt2 < 2; ++nt2)
      bcol[nt2] = bias[n0 + wn * 64 + nt2 * 32 + lr31];
    float* my = (float*)(lds + wid * 8704);       // 4 x 8704 = 34816 <= 36K
#pragma unroll
    for (int mt2 = 0; mt2 < 2; ++mt2) {
#pragma unroll
      for (int nt2 = 0; nt2 < 2; ++nt2)
#pragma unroll
        for (int reg = 0; reg < 16; ++reg) {
          const int row = (reg & 3) + 8 * (reg >> 2) + 4 * lkb;
          my[row * 68 + nt2 * 32 + lr31] = acc[mt2][nt2][reg] + bcol[nt2];
        }
#pragma unroll
      for (int it = 0; it < 2; ++it) {
        const int idx = it * 64 + lane;           // 0..127
        const int row = idx >> 2, seg = idx & 3;
        const float* s = my + row * 68 + seg * 16;
        uint32_t w[4];
#pragma unroll
        for (int q = 0; q < 4; ++q) {
          uint32_t pk = 0;
          pk = __builtin_amdgcn_cvt_pk_fp8_f32(s[q*4+0], s[q*4+1], pk, false);
          pk = __builtin_amdgcn_cvt_pk_fp8_f32(s[q*4+2], s[q*4+3], pk, true);
          w[q] = pk;
        }
        char* orow = plane + (size_t)(wm * 64 + mt2 * 32 + row) * 64 + seg * 16;
        *(uint4*)orow = *(uint4*)w;
      }
    }
  } else {
#pragma unroll
    for (int nt2 = 0; nt2 < 2; ++nt2) {
      const int col = n0 + wn * 64 + nt2 * 32 + lr31;
      const float bcol = bias[col];
      float gcol = 0.f;
      if constexpr (MODE == 2) gcol = gammav[col];
#pragma unroll
      for (int mt2 = 0; mt2 < 2; ++mt2)
#pragma unroll
        for (int reg = 0; reg < 16; ++reg) {
          const int row = m0 + wm * 64 + mt2 * 32
                        + (reg & 3) + 8 * (reg >> 2) + 4 * lkb;
          const size_t o = (size_t)row * N + col;
          if constexpr (MODE == 1)
            ((float*)Cout)[o] = acc[mt2][nt2][reg] * oscale + bcol;
          else
            ((float*)Cout)[o] = resid[o] + gcol * (acc[mt2][nt2][reg] + bcol);
        }
    }
  }
}

// ---------------- softmax over 12 + pack sampling params --------------------
__global__ void softmax_pack(const float* __restrict__ raw,
                             const float* __restrict__ refp,
                             float4* __restrict__ params) {
  const int t = blockIdx.x * 256 + threadIdx.x;       // [0, MQ*NHD)
  const int h = t % NHD, nq = t / NHD;
  const float* p = raw + (size_t)nq * CAT_N + AW_OFF + h * 12;
  float v[12], m = -1e30f;
#pragma unroll
  for (int j = 0; j < 12; ++j) { v[j] = p[j]; m = fmaxf(m, v[j]); }
  float s = 0.f;
#pragma unroll
  for (int j = 0; j < 12; ++j) { v[j] = __expf(v[j] - m); s += v[j]; }
  const float inv = 1.f / s;
  const float* op = raw + (size_t)nq * CAT_N + h * 24;
  const float* rp = refp + (size_t)nq * (NLVL * 2);
  float4* out = params + (size_t)t * 12;
  const float Wf[3] = {128.f, 64.f, 32.f};
#pragma unroll
  for (int l = 0; l < NLVL; ++l) {
    const float rxw = rp[2 * l] * Wf[l] - 0.5f;
    const float ryw = rp[2 * l + 1] * Wf[l] - 0.5f;
#pragma unroll
    for (int pt = 0; pt < NPT; ++pt) {
      float4 o4;
      o4.x = rxw + op[(l * 4 + pt) * 2 + 0];
      o4.y = ryw + op[(l * 4 + pt) * 2 + 1];
      o4.z = v[l * 4 + pt] * inv;
      o4.w = 0.f;
      out[l * 4 + pt] = o4;
    }
  }
}

// ------------- deformable sampling: 16 channels/lane, fp8 ------------------
__global__ __launch_bounds__(256) void deform_grp16(
    const char* __restrict__ vbytes, const float4* __restrict__ params,
    char* __restrict__ samp)
{
  const int j = blockIdx.x;                   // 3072 blocks
  const int x = j & 7, k = j >> 3;            // k in [0,384)
  const int g = x + ((k >> 6) << 3);          // plane, pinned to XCD x
  const int i = k & 63;                       // block within group
  const int n = g / NHD, h = g - n * NHD;
  const int wid = threadIdx.x >> 6, lane = threadIdx.x & 63;
  const int qi = lane >> 2, ci = lane & 3;
  const int q  = i * 64 + wid * 16 + qi;      // [0, 4096)
  const int nq = n * LQ + q;
  const float4* __restrict__ pp = params + ((size_t)nq * NHD + h) * 12;
  const uint32_t base0 = (uint32_t)g * (uint32_t)(LIN * 64)
                       + ((uint32_t)ci << 4);

  float acc[16];
#pragma unroll
  for (int c = 0; c < 16; ++c) acc[c] = 0.f;

  const int      Wl[3]  = {128, 64, 32};
  const uint32_t STb[3] = {0u, 16384u * 64u, 20480u * 64u};

#pragma unroll
  for (int l = 0; l < NLVL; ++l) {
    const int W_ = Wl[l];
    const uint32_t base = base0 + STb[l];
#pragma unroll
    for (int p = 0; p < NPT; ++p) {
      const float4 pt = pp[l * 4 + p];
      const float fx = floorf(pt.x), fy = floorf(pt.y);
      const float tx = pt.x - fx,   ty = pt.y - fy;
      const int x0 = (int)fx, y0 = (int)fy;
      const int x1 = x0 + 1,  y1 = y0 + 1;
      const float wx0 = ((uint32_t)x0 < (uint32_t)W_) ? (1.f - tx) : 0.f;
      const float wx1 = ((uint32_t)x1 < (uint32_t)W_) ? tx : 0.f;
      const float wy0 = ((uint32_t)y0 < (uint32_t)W_) ? pt.z * (1.f - ty) : 0.f;
      const float wy1 = ((uint32_t)y1 < (uint32_t)W_) ? pt.z * ty : 0.f;
      const int xc0 = min(max(x0, 0), W_ - 1);
      const int xc1 = min(max(x1, 0), W_ - 1);
      const int yr0 = min(max(y0, 0), W_ - 1) * W_;
      const int yr1 = min(max(y1, 0), W_ - 1) * W_;
      const float cw[4] = {wy0 * wx0, wy0 * wx1, wy1 * wx0, wy1 * wx1};
      const uint4 G0 = *(const uint4*)(vbytes + base + (uint32_t)(yr0 + xc0) * 64u);
      const uint4 G1 = *(const uint4*)(vbytes + base + (uint32_t)(yr0 + xc1) * 64u);
      const uint4 G2 = *(const uint4*)(vbytes + base + (uint32_t)(yr1 + xc0) * 64u);
      const uint4 G3 = *(const uint4*)(vbytes + base + (uint32_t)(yr1 + xc1) * 64u);
      const uint4 GG[4] = {G0, G1, G2, G3};
#pragma unroll
      for (int cnr = 0; cnr < 4; ++cnr) {
        const uint32_t wds[4] = {GG[cnr].x, GG[cnr].y, GG[cnr].z, GG[cnr].w};
        const float wgt = cw[cnr];
#pragma unroll
        for (int wd = 0; wd < 4; ++wd) {
          f32x2 lo = __builtin_amdgcn_cvt_pk_f32_fp8(wds[wd], false);
          f32x2 hi = __builtin_amdgcn_cvt_pk_f32_fp8(wds[wd], true);
          acc[wd * 4 + 0] += lo[0] * wgt;
          acc[wd * 4 + 1] += lo[1] * wgt;
          acc[wd * 4 + 2] += hi[0] * wgt;
          acc[wd * 4 + 3] += hi[1] * wgt;
        }
      }
    }
  }

  uint32_t out[4];
#pragma unroll
  for (int wd = 0; wd < 4; ++wd) {
    uint32_t pk = 0;
    pk = __builtin_amdgcn_cvt_pk_fp8_f32(acc[wd*4+0], acc[wd*4+1], pk, false);
    pk = __builtin_amdgcn_cvt_pk_fp8_f32(acc[wd*4+2], acc[wd*4+3], pk, true);
    out[wd] = pk;
  }
  *(uint4*)(samp + (size_t)nq * CDIM + h * HDIM + ci * 16) = *(uint4*)out;
}

// ---------------- host ------------------------------------------------------
extern "C" void kernel_launch(void* const* d_in, const int* in_sizes, int n_in,
                              void* d_out, int out_size, void* d_ws, size_t ws_size,
                              hipStream_t stream) {
  const float* query = (const float*)d_in[0];
  const float* refp  = (const float*)d_in[1];
  const float* feat  = (const float*)d_in[2];
  const float* qn_w  = (const float*)d_in[3];
  const float* qn_b  = (const float*)d_in[4];
  const float* fn_w  = (const float*)d_in[5];
  const float* fn_b  = (const float*)d_in[6];
  const float* gamma = (const float*)d_in[7];
  const float* so_w  = (const float*)d_in[8];
  const float* so_b  = (const float*)d_in[9];
  const float* aw_w  = (const float*)d_in[10];
  const float* aw_b  = (const float*)d_in[11];
  const float* vp_w  = (const float*)d_in[12];
  const float* vp_b  = (const float*)d_in[13];
  const float* op_w  = (const float*)d_in[14];
  const float* op_b  = (const float*)d_in[15];

  char* ws = (char*)d_ws;
  size_t off = 0;
  auto alloc = [&](size_t bytes) {
    char* p = ws + off;
    off = (off + bytes + 255) & ~(size_t)255;
    return p;
  };
  char*   q_f8   = (char*)alloc((size_t)MQ * CDIM);
  char*   val_f8 = (char*)alloc((size_t)MF * CDIM);        // [48][LIN][64] e4m3
  char*   vp_w8  = (char*)alloc((size_t)CDIM * CDIM);
  char*   op_w8  = (char*)alloc((size_t)CDIM * CDIM);
  char*   cat_w8 = (char*)alloc((size_t)CAT_N * CDIM);     // x16 pre-scaled
  float*  cat_bp = (float*)alloc(CAT_N * 4);

  // region R: f_f8 (phase A) aliases the phase-B buffers
  const size_t r = off;
  char* f_f8 = ws + r;
  const size_t f_end = r + (size_t)MF * CDIM;
  size_t o2 = r;
  float*  raw     = (float*)(ws + o2);  o2 += (size_t)MQ * CAT_N * 4;
  float4* params  = (float4*)(ws + o2); o2 += (size_t)MQ * NHD * 12 * 16;
  char*   samp8   = (char*)(ws + o2);   o2 += (size_t)MQ * CDIM;
  const size_t need = (f_end > o2) ? f_end : o2;
  if (ws_size < need) return;   // ~180 MB required

  // 1) all weight prep in one launch (4 fp8 transposes + cat bias)
  prep_weights<<<1537, 256, 0, stream>>>(vp_w, op_w, so_w, aw_w, so_b, aw_b,
                                         vp_w8, op_w8, cat_w8, cat_bp);

  // 2) layernorms (1 wave/row) -> fp8
  ln_wave<<<MQ / 4, 256, 0, stream>>>(query, qn_w, qn_b, q_f8);
  ln_wave<<<MF / 4, 256, 0, stream>>>(feat, fn_w, fn_b, f_f8);

  // 3) value = LN(feat) @ vp_w + vp_b   (MX 32x32x64, fp8 head-major out)
  gemm_mx<0><<<(MF / 128) * (CDIM / 128), 256, 0, stream>>>(
      f_f8, vp_w8, vp_b, val_f8, MF, CDIM, CDIM, CDIM / 128,
      1.f, nullptr, nullptr);

  // 4) fused so|aw GEMM (MX, f32 out, /16 descale)
  gemm_mx<1><<<(MQ / 128) * (CAT_N / 128), 256, 0, stream>>>(
      q_f8, cat_w8, cat_bp, raw, MQ, CAT_N, CDIM, CAT_N / 128,
      1.f / WSCL, nullptr, nullptr);

  // 5) softmax + pack {px,py,a} per (q,h,l,p)
  softmax_pack<<<(MQ * NHD) / 256, 256, 0, stream>>>(raw, refp, params);

  // 6) deformable sampling -> samp fp8 [MQ][768]  (16 ch/lane)
  deform_grp16<<<48 * 64, 256, 0, stream>>>(val_f8, params, samp8);

  // 7) out = query + gamma * (samp @ op_w + op_b)   (MX, fused f32 epilogue)
  gemm_mx<2><<<(MQ / 128) * (CDIM / 128), 256, 0, stream>>>(
      samp8, op_w8, op_b, (float*)d_out, MQ, CDIM, CDIM, CDIM / 128,
      1.f, query, gamma);
}

// Round 16
// 321.061 us; speedup vs baseline: 1.0049x; 1.0049x over previous
//
#include <hip/hip_runtime.h>
#include <hip/hip_bf16.h>
#include <stdint.h>

// ---------------- problem constants (fixed by setup_inputs) ----------------
#define NHD   12        // heads
#define NPT   4         // points
#define CDIM  768
#define HDIM  64
#define NLVL  3
#define LQ    4096
#define NB    4
#define LIN   21504     // 128*128 + 64*64 + 32*32
#define MQ    (NB*LQ)   // 16384 query rows
#define MF    (NB*LIN)  // 86016 feat rows
#define CAT_N 512       // fused so(288) | aw(144 real + pad)
#define AW_OFF 288
#define WSCL  16.f      // so/aw weight pre-scale (fp8 denormal avoidance)

typedef float  f32x4  __attribute__((ext_vector_type(4)));
typedef float  f32x2  __attribute__((ext_vector_type(2)));
typedef float  f32x16 __attribute__((ext_vector_type(16)));
typedef int    i32x8  __attribute__((ext_vector_type(8)));

__device__ __forceinline__ i32x8 mk8(uint4 lo, uint4 hi) {
  i32x8 v;
  v[0] = (int)lo.x; v[1] = (int)lo.y; v[2] = (int)lo.z; v[3] = (int)lo.w;
  v[4] = (int)hi.x; v[5] = (int)hi.y; v[6] = (int)hi.z; v[7] = (int)hi.w;
  return v;
}

// ------- merged weight prep: 4 transposes (fp8) + cat bias, 1 launch -------
__global__ __launch_bounds__(256) void prep_weights(
    const float* __restrict__ vp_w, const float* __restrict__ op_w,
    const float* __restrict__ so_w, const float* __restrict__ aw_w,
    const float* __restrict__ so_b, const float* __restrict__ aw_b,
    char* __restrict__ vp_w8, char* __restrict__ op_w8,
    char* __restrict__ cat_w8, float* __restrict__ cat_bp)
{
  const int b = blockIdx.x;
  if (b == 1536) {
    const int i = threadIdx.x;
#pragma unroll
    for (int it = 0; it < 2; ++it) {
      const int idx = i + it * 256;
      float v = 0.f;
      if (idx < 288) v = so_b[idx];
      else if (idx < 432) v = aw_b[idx - AW_OFF];
      cat_bp[idx] = v;
    }
    return;
  }
  const float* W; char* Wt; int Nsrc, rowoff; float scale;
  int lb;
  if (b < 576)       { W = vp_w; Wt = vp_w8;  Nsrc = 768; rowoff = 0;   scale = 1.f;  lb = b; }
  else if (b < 1152) { W = op_w; Wt = op_w8;  Nsrc = 768; rowoff = 0;   scale = 1.f;  lb = b - 576; }
  else if (b < 1368) { W = so_w; Wt = cat_w8; Nsrc = 288; rowoff = 0;   scale = WSCL; lb = b - 1152; }
  else               { W = aw_w; Wt = cat_w8; Nsrc = 144; rowoff = 288; scale = WSCL; lb = b - 1368; }

  __shared__ float t[32][33];
  const int k0 = (lb % 24) * 32;
  const int n0 = (lb / 24) * 32;
  const int tx = threadIdx.x & 31, ty = threadIdx.x >> 5;
#pragma unroll
  for (int i = ty; i < 32; i += 8) {
    const int n = n0 + tx;
    t[i][tx] = (n < Nsrc) ? W[(size_t)(k0 + i) * Nsrc + n] * scale : 0.f;
  }
  __syncthreads();
#pragma unroll
  for (int i = ty; i < 32; i += 8) {
    const int n = rowoff + n0 + i;
    uint32_t pk = __builtin_amdgcn_cvt_pk_fp8_f32(t[tx][i], 0.f, 0, false);
    Wt[(size_t)n * CDIM + k0 + tx] = (char)(pk & 0xff);
  }
}

// ---------------- LayerNorm, 1 wave/row, fp8 e4m3 out ----------------------
__global__ __launch_bounds__(256) void ln_wave(const float* __restrict__ x,
                                               const float* __restrict__ w,
                                               const float* __restrict__ b,
                                               char* __restrict__ y) {
  const int row  = blockIdx.x * 4 + (threadIdx.x >> 6);
  const int lane = threadIdx.x & 63;
  const float4* xr = (const float4*)(x + (size_t)row * CDIM);
  float4 v[3];
  v[0] = xr[lane]; v[1] = xr[lane + 64]; v[2] = xr[lane + 128];
  float s1 = 0.f, s2 = 0.f;
#pragma unroll
  for (int i = 0; i < 3; ++i) {
    s1 += v[i].x + v[i].y + v[i].z + v[i].w;
    s2 += v[i].x*v[i].x + v[i].y*v[i].y + v[i].z*v[i].z + v[i].w*v[i].w;
  }
#pragma unroll
  for (int o = 32; o > 0; o >>= 1) { s1 += __shfl_xor(s1, o); s2 += __shfl_xor(s2, o); }
  const float mu = s1 * (1.f / CDIM);
  const float rs = rsqrtf(s2 * (1.f / CDIM) - mu * mu + 1e-6f);
#pragma unroll
  for (int i = 0; i < 3; ++i) {
    const float4 w4 = ((const float4*)w)[lane + i * 64];
    const float4 b4 = ((const float4*)b)[lane + i * 64];
    const float o0 = (v[i].x - mu) * rs * w4.x + b4.x;
    const float o1 = (v[i].y - mu) * rs * w4.y + b4.y;
    const float o2 = (v[i].z - mu) * rs * w4.z + b4.z;
    const float o3 = (v[i].w - mu) * rs * w4.w + b4.w;
    uint32_t pk = 0;
    pk = __builtin_amdgcn_cvt_pk_fp8_f32(o0, o1, pk, false);
    pk = __builtin_amdgcn_cvt_pk_fp8_f32(o2, o3, pk, true);
    ((uint32_t*)(y + (size_t)row * CDIM))[lane + i * 64] = pk;
  }
}

// ======== 128x128 MX fp8 GEMM: A via LDS (3-buf), B reg-dbuf from L2 =======
// C = A[M][K](e4m3) * Wt[N][K](e4m3)^T. Unity e8m0 scales (0x7F) = exact fp8.
// 256 thr = 4 waves (2M x 2N), per-wave 64x64 = 2x2 of 32x32.
// A: 3 LDS bufs x 8 KB (chunk swizzle p^(r&3)); stage tile t+2 during t.
// B: REGISTER double-buffer -- bn = B(t+1) issued at top of iter t, consumed
//   next iter => a full tile of MFMA+stage covers the L2 latency (fixes R15,
//   which used B(t) in-iter and stalled ~250 cyc per tile).
// VMEM counting (4 B-loads + 2 A-stage insts per iter):
//   prologue: stageA(0),stageA(1) -> vmcnt(2) => A(0) landed; peel B(0).
//   end of iter t: in-flight = stageA(t+1)[2 oldest] + bn[4] + stageA(t+2)[2]
//     -> vmcnt(6) => A(t+1) landed, B still in flight.
//   t = nk-2: no stageA(t+2) -> vmcnt(4). t = nk-1: none.
// Operand frag: lane l = row (l&31), k = (l>>5)*32 + e. C/D (verified R11):
// col = lane&31, row = (reg&3)+8*(reg>>2)+4*(lane>>5).
// MODE 0: fp8 head-major value store; 1: f32 acc*oscale+bias; 2: resid+gamma.
template<int MODE>
__global__ __launch_bounds__(256, 3) void gemm_mx(
    const char* __restrict__ A, const char* __restrict__ Wt,
    const float* __restrict__ bias, void* __restrict__ Cout,
    int M, int N, int K, int nTN, float oscale,
    const float* __restrict__ resid, const float* __restrict__ gammav)
{
  __shared__ __align__(16) char lds[36864];   // 3 x 8 KiB bufs + epilogue ovl

  int bid = blockIdx.x;
  const int nwg = gridDim.x;
  if ((nwg & 7) == 0) {                 // XCD-chunked swizzle (bijective)
    const int chunk = nwg >> 3;
    bid = (bid & 7) * chunk + (bid >> 3);
  }
  const int mt = bid / nTN, ntl = bid - mt * nTN;
  const int m0 = mt * 128, n0 = ntl * 128;
  const int tid  = threadIdx.x;
  const int lane = tid & 63, wid = tid >> 6;
  const int wm = wid >> 1, wn = wid & 1;          // 2x2 wave grid
  const int lr31 = lane & 31, lkb = lane >> 5;

  f32x16 acc[2][2] = {};

  // stage A half of tile kt into buf (2 x 16B gload_lds per thread)
  auto stageA = [&](int kt, int buf) {
    const int k0 = kt * 64;
    char* dst0 = lds + buf * 8192;
#pragma unroll
    for (int it = 0; it < 2; ++it) {
      const int i = it * 256 + tid;              // chunk 0..511
      const int r = i >> 2, p = i & 3;
      const int c = p ^ (r & 3);                 // source chunk (involution)
      const char* src = A + (size_t)(m0 + r) * K + k0 + c * 16;
      char* dst = dst0 + (it * 256 + wid * 64) * 16;   // + lane*16 by HW
      __builtin_amdgcn_global_load_lds(
          (const __attribute__((address_space(1))) uint32_t*)src,
          (__attribute__((address_space(3))) uint32_t*)dst, 16, 0, 0);
    }
  };
  auto rdA = [&](int buf, int row) -> i32x8 {
    const char* base = lds + buf * 8192 + row * 64;
    const int s = row & 3;
    const uint4 lo = *(const uint4*)(base + ((2 * lkb)     ^ s) * 16);
    const uint4 hi = *(const uint4*)(base + ((2 * lkb + 1) ^ s) * 16);
    return mk8(lo, hi);
  };
  // B fragment straight from global (L2-resident weights)
  auto rdB = [&](int kt, int nt2) -> i32x8 {
    const char* p = Wt + (size_t)(n0 + wn * 64 + nt2 * 32 + lr31) * K
                       + kt * 64 + lkb * 32;
    const uint4 lo = *(const uint4*)p;
    const uint4 hi = *(const uint4*)(p + 16);
    return mk8(lo, hi);
  };

  const int nk = K >> 6;                          // 12 K-tiles
  // prologue: stage A tiles 0,1; wait tile 0 (oldest 2 of 4)
  stageA(0, 0); stageA(1, 1);
  asm volatile("s_waitcnt vmcnt(2)" ::: "memory");
  __builtin_amdgcn_s_barrier();
  asm volatile("" ::: "memory");
  // peel B(0) (one-time L2 latency, hidden partially under first rdA)
  i32x8 b0 = rdB(0, 0), b1 = rdB(0, 1);

  for (int t = 0; t < nk; ++t) {
    const int cur = t % 3;
    i32x8 bn0, bn1;
    if (t + 1 < nk) { bn0 = rdB(t + 1, 0); bn1 = rdB(t + 1, 1); }
    const i32x8 a0 = rdA(cur, wm * 64 + lr31);
    const i32x8 a1 = rdA(cur, wm * 64 + 32 + lr31);
    if (t + 2 < nk) stageA(t + 2, (t + 2) % 3);
    __builtin_amdgcn_s_setprio(1);
    acc[0][0] = __builtin_amdgcn_mfma_scale_f32_32x32x64_f8f6f4(
        a0, b0, acc[0][0], 0, 0, 0, 0x7F7F7F7F, 0, 0x7F7F7F7F);
    acc[0][1] = __builtin_amdgcn_mfma_scale_f32_32x32x64_f8f6f4(
        a0, b1, acc[0][1], 0, 0, 0, 0x7F7F7F7F, 0, 0x7F7F7F7F);
    acc[1][0] = __builtin_amdgcn_mfma_scale_f32_32x32x64_f8f6f4(
        a1, b0, acc[1][0], 0, 0, 0, 0x7F7F7F7F, 0, 0x7F7F7F7F);
    acc[1][1] = __builtin_amdgcn_mfma_scale_f32_32x32x64_f8f6f4(
        a1, b1, acc[1][1], 0, 0, 0, 0x7F7F7F7F, 0, 0x7F7F7F7F);
    __builtin_amdgcn_s_setprio(0);
    if (t + 1 < nk) { b0 = bn0; b1 = bn1; }
    if (t + 2 < nk)      asm volatile("s_waitcnt vmcnt(6)" ::: "memory"); // A(t+1) landed
    else if (t + 1 < nk) asm volatile("s_waitcnt vmcnt(4)" ::: "memory"); // tail
    __builtin_amdgcn_s_barrier();
    asm volatile("" ::: "memory");
  }

  // ---- epilogue ----
  if constexpr (MODE == 0) {
    // fp8 head-major value store via per-wave LDS staging ([32][68] f32)
    const int head  = (n0 + wn * 64) >> 6;
    const int n_img = (unsigned)m0 / LIN;         // LIN%128==0: no crossing
    char* plane = (char*)Cout + ((size_t)(n_img * NHD + head) * LIN
                                 + (m0 - n_img * LIN)) * 64;
    float bcol[2];
#pragma unroll
    for (int nt2 = 0; nt2 < 2; ++nt2)
      bcol[nt2] = bias[n0 + wn * 64 + nt2 * 32 + lr31];
    float* my = (float*)(lds + wid * 8704);       // 4 x 8704 = 34816 <= 36K
#pragma unroll
    for (int mt2 = 0; mt2 < 2; ++mt2) {
#pragma unroll
      for (int nt2 = 0; nt2 < 2; ++nt2)
#pragma unroll
        for (int reg = 0; reg < 16; ++reg) {
          const int row = (reg & 3) + 8 * (reg >> 2) + 4 * lkb;
          my[row * 68 + nt2 * 32 + lr31] = acc[mt2][nt2][reg] + bcol[nt2];
        }
#pragma unroll
      for (int it = 0; it < 2; ++it) {
        const int idx = it * 64 + lane;           // 0..127
        const int row = idx >> 2, seg = idx & 3;
        const float* s = my + row * 68 + seg * 16;
        uint32_t w[4];
#pragma unroll
        for (int q = 0; q < 4; ++q) {
          uint32_t pk = 0;
          pk = __builtin_amdgcn_cvt_pk_fp8_f32(s[q*4+0], s[q*4+1], pk, false);
          pk = __builtin_amdgcn_cvt_pk_fp8_f32(s[q*4+2], s[q*4+3], pk, true);
          w[q] = pk;
        }
        char* orow = plane + (size_t)(wm * 64 + mt2 * 32 + row) * 64 + seg * 16;
        *(uint4*)orow = *(uint4*)w;
      }
    }
  } else {
#pragma unroll
    for (int nt2 = 0; nt2 < 2; ++nt2) {
      const int col = n0 + wn * 64 + nt2 * 32 + lr31;
      const float bcol = bias[col];
      float gcol = 0.f;
      if constexpr (MODE == 2) gcol = gammav[col];
#pragma unroll
      for (int mt2 = 0; mt2 < 2; ++mt2)
#pragma unroll
        for (int reg = 0; reg < 16; ++reg) {
          const int row = m0 + wm * 64 + mt2 * 32
                        + (reg & 3) + 8 * (reg >> 2) + 4 * lkb;
          const size_t o = (size_t)row * N + col;
          if constexpr (MODE == 1)
            ((float*)Cout)[o] = acc[mt2][nt2][reg] * oscale + bcol;
          else
            ((float*)Cout)[o] = resid[o] + gcol * (acc[mt2][nt2][reg] + bcol);
        }
    }
  }
}

// ---------------- softmax over 12 + pack sampling params --------------------
__global__ void softmax_pack(const float* __restrict__ raw,
                             const float* __restrict__ refp,
                             float4* __restrict__ params) {
  const int t = blockIdx.x * 256 + threadIdx.x;       // [0, MQ*NHD)
  const int h = t % NHD, nq = t / NHD;
  const float* p = raw + (size_t)nq * CAT_N + AW_OFF + h * 12;
  float v[12], m = -1e30f;
#pragma unroll
  for (int j = 0; j < 12; ++j) { v[j] = p[j]; m = fmaxf(m, v[j]); }
  float s = 0.f;
#pragma unroll
  for (int j = 0; j < 12; ++j) { v[j] = __expf(v[j] - m); s += v[j]; }
  const float inv = 1.f / s;
  const float* op = raw + (size_t)nq * CAT_N + h * 24;
  const float* rp = refp + (size_t)nq * (NLVL * 2);
  float4* out = params + (size_t)t * 12;
  const float Wf[3] = {128.f, 64.f, 32.f};
#pragma unroll
  for (int l = 0; l < NLVL; ++l) {
    const float rxw = rp[2 * l] * Wf[l] - 0.5f;
    const float ryw = rp[2 * l + 1] * Wf[l] - 0.5f;
#pragma unroll
    for (int pt = 0; pt < NPT; ++pt) {
      float4 o4;
      o4.x = rxw + op[(l * 4 + pt) * 2 + 0];
      o4.y = ryw + op[(l * 4 + pt) * 2 + 1];
      o4.z = v[l * 4 + pt] * inv;
      o4.w = 0.f;
      out[l * 4 + pt] = o4;
    }
  }
}

// ------------- deformable sampling: 16 channels/lane, fp8 ------------------
__global__ __launch_bounds__(256) void deform_grp16(
    const char* __restrict__ vbytes, const float4* __restrict__ params,
    char* __restrict__ samp)
{
  const int j = blockIdx.x;                   // 3072 blocks
  const int x = j & 7, k = j >> 3;            // k in [0,384)
  const int g = x + ((k >> 6) << 3);          // plane, pinned to XCD x
  const int i = k & 63;                       // block within group
  const int n = g / NHD, h = g - n * NHD;
  const int wid = threadIdx.x >> 6, lane = threadIdx.x & 63;
  const int qi = lane >> 2, ci = lane & 3;
  const int q  = i * 64 + wid * 16 + qi;      // [0, 4096)
  const int nq = n * LQ + q;
  const float4* __restrict__ pp = params + ((size_t)nq * NHD + h) * 12;
  const uint32_t base0 = (uint32_t)g * (uint32_t)(LIN * 64)
                       + ((uint32_t)ci << 4);

  float acc[16];
#pragma unroll
  for (int c = 0; c < 16; ++c) acc[c] = 0.f;

  const int      Wl[3]  = {128, 64, 32};
  const uint32_t STb[3] = {0u, 16384u * 64u, 20480u * 64u};

#pragma unroll
  for (int l = 0; l < NLVL; ++l) {
    const int W_ = Wl[l];
    const uint32_t base = base0 + STb[l];
#pragma unroll
    for (int p = 0; p < NPT; ++p) {
      const float4 pt = pp[l * 4 + p];
      const float fx = floorf(pt.x), fy = floorf(pt.y);
      const float tx = pt.x - fx,   ty = pt.y - fy;
      const int x0 = (int)fx, y0 = (int)fy;
      const int x1 = x0 + 1,  y1 = y0 + 1;
      const float wx0 = ((uint32_t)x0 < (uint32_t)W_) ? (1.f - tx) : 0.f;
      const float wx1 = ((uint32_t)x1 < (uint32_t)W_) ? tx : 0.f;
      const float wy0 = ((uint32_t)y0 < (uint32_t)W_) ? pt.z * (1.f - ty) : 0.f;
      const float wy1 = ((uint32_t)y1 < (uint32_t)W_) ? pt.z * ty : 0.f;
      const int xc0 = min(max(x0, 0), W_ - 1);
      const int xc1 = min(max(x1, 0), W_ - 1);
      const int yr0 = min(max(y0, 0), W_ - 1) * W_;
      const int yr1 = min(max(y1, 0), W_ - 1) * W_;
      const float cw[4] = {wy0 * wx0, wy0 * wx1, wy1 * wx0, wy1 * wx1};
      const uint4 G0 = *(const uint4*)(vbytes + base + (uint32_t)(yr0 + xc0) * 64u);
      const uint4 G1 = *(const uint4*)(vbytes + base + (uint32_t)(yr0 + xc1) * 64u);
      const uint4 G2 = *(const uint4*)(vbytes + base + (uint32_t)(yr1 + xc0) * 64u);
      const uint4 G3 = *(const uint4*)(vbytes + base + (uint32_t)(yr1 + xc1) * 64u);
      const uint4 GG[4] = {G0, G1, G2, G3};
#pragma unroll
      for (int cnr = 0; cnr < 4; ++cnr) {
        const uint32_t wds[4] = {GG[cnr].x, GG[cnr].y, GG[cnr].z, GG[cnr].w};
        const float wgt = cw[cnr];
#pragma unroll
        for (int wd = 0; wd < 4; ++wd) {
          f32x2 lo = __builtin_amdgcn_cvt_pk_f32_fp8(wds[wd], false);
          f32x2 hi = __builtin_amdgcn_cvt_pk_f32_fp8(wds[wd], true);
          acc[wd * 4 + 0] += lo[0] * wgt;
          acc[wd * 4 + 1] += lo[1] * wgt;
          acc[wd * 4 + 2] += hi[0] * wgt;
          acc[wd * 4 + 3] += hi[1] * wgt;
        }
      }
    }
  }

  uint32_t out[4];
#pragma unroll
  for (int wd = 0; wd < 4; ++wd) {
    uint32_t pk = 0;
    pk = __builtin_amdgcn_cvt_pk_fp8_f32(acc[wd*4+0], acc[wd*4+1], pk, false);
    pk = __builtin_amdgcn_cvt_pk_fp8_f32(acc[wd*4+2], acc[wd*4+3], pk, true);
    out[wd] = pk;
  }
  *(uint4*)(samp + (size_t)nq * CDIM + h * HDIM + ci * 16) = *(uint4*)out;
}

// ---------------- host ------------------------------------------------------
extern "C" void kernel_launch(void* const* d_in, const int* in_sizes, int n_in,
                              void* d_out, int out_size, void* d_ws, size_t ws_size,
                              hipStream_t stream) {
  const float* query = (const float*)d_in[0];
  const float* refp  = (const float*)d_in[1];
  const float* feat  = (const float*)d_in[2];
  const float* qn_w  = (const float*)d_in[3];
  const float* qn_b  = (const float*)d_in[4];
  const float* fn_w  = (const float*)d_in[5];
  const float* fn_b  = (const float*)d_in[6];
  const float* gamma = (const float*)d_in[7];
  const float* so_w  = (const float*)d_in[8];
  const float* so_b  = (const float*)d_in[9];
  const float* aw_w  = (const float*)d_in[10];
  const float* aw_b  = (const float*)d_in[11];
  const float* vp_w  = (const float*)d_in[12];
  const float* vp_b  = (const float*)d_in[13];
  const float* op_w  = (const float*)d_in[14];
  const float* op_b  = (const float*)d_in[15];

  char* ws = (char*)d_ws;
  size_t off = 0;
  auto alloc = [&](size_t bytes) {
    char* p = ws + off;
    off = (off + bytes + 255) & ~(size_t)255;
    return p;
  };
  char*   q_f8   = (char*)alloc((size_t)MQ * CDIM);
  char*   val_f8 = (char*)alloc((size_t)MF * CDIM);        // [48][LIN][64] e4m3
  char*   vp_w8  = (char*)alloc((size_t)CDIM * CDIM);
  char*   op_w8  = (char*)alloc((size_t)CDIM * CDIM);
  char*   cat_w8 = (char*)alloc((size_t)CAT_N * CDIM);     // x16 pre-scaled
  float*  cat_bp = (float*)alloc(CAT_N * 4);

  // region R: f_f8 (phase A) aliases the phase-B buffers
  const size_t r = off;
  char* f_f8 = ws + r;
  const size_t f_end = r + (size_t)MF * CDIM;
  size_t o2 = r;
  float*  raw     = (float*)(ws + o2);  o2 += (size_t)MQ * CAT_N * 4;
  float4* params  = (float4*)(ws + o2); o2 += (size_t)MQ * NHD * 12 * 16;
  char*   samp8   = (char*)(ws + o2);   o2 += (size_t)MQ * CDIM;
  const size_t need = (f_end > o2) ? f_end : o2;
  if (ws_size < need) return;   // ~180 MB required

  // 1) all weight prep in one launch (4 fp8 transposes + cat bias)
  prep_weights<<<1537, 256, 0, stream>>>(vp_w, op_w, so_w, aw_w, so_b, aw_b,
                                         vp_w8, op_w8, cat_w8, cat_bp);

  // 2) layernorms (1 wave/row) -> fp8
  ln_wave<<<MQ / 4, 256, 0, stream>>>(query, qn_w, qn_b, q_f8);
  ln_wave<<<MF / 4, 256, 0, stream>>>(feat, fn_w, fn_b, f_f8);

  // 3) value = LN(feat) @ vp_w + vp_b   (MX 32x32x64, fp8 head-major out)
  gemm_mx<0><<<(MF / 128) * (CDIM / 128), 256, 0, stream>>>(
      f_f8, vp_w8, vp_b, val_f8, MF, CDIM, CDIM, CDIM / 128,
      1.f, nullptr, nullptr);

  // 4) fused so|aw GEMM (MX, f32 out, /16 descale)
  gemm_mx<1><<<(MQ / 128) * (CAT_N / 128), 256, 0, stream>>>(
      q_f8, cat_w8, cat_bp, raw, MQ, CAT_N, CDIM, CAT_N / 128,
      1.f / WSCL, nullptr, nullptr);

  // 5) softmax + pack {px,py,a} per (q,h,l,p)
  softmax_pack<<<(MQ * NHD) / 256, 256, 0, stream>>>(raw, refp, params);

  // 6) deformable sampling -> samp fp8 [MQ][768]  (16 ch/lane)
  deform_grp16<<<48 * 64, 256, 0, stream>>>(val_f8, params, samp8);

  // 7) out = query + gamma * (samp @ op_w + op_b)   (MX, fused f32 epilogue)
  gemm_mx<2><<<(MQ / 128) * (CDIM / 128), 256, 0, stream>>>(
      samp8, op_w8, op_b, (float*)d_out, MQ, CDIM, CDIM, CDIM / 128,
      1.f, query, gamma);
}

// Round 17
// 271.480 us; speedup vs baseline: 1.1885x; 1.1826x over previous
//
#include <hip/hip_runtime.h>
#include <hip/hip_bf16.h>
#include <stdint.h>

// ---------------- problem constants (fixed by setup_inputs) ----------------
#define NHD   12        // heads
#define NPT   4         // points
#define CDIM  768
#define HDIM  64
#define NLVL  3
#define LQ    4096
#define NB    4
#define LIN   21504     // 128*128 + 64*64 + 32*32
#define MQ    (NB*LQ)   // 16384 query rows
#define MF    (NB*LIN)  // 86016 feat rows
#define CAT_N 512       // fused so(288) | aw(144 real + pad)
#define AW_OFF 288
#define WSCL  16.f      // so/aw weight pre-scale (fp8 denormal avoidance)

typedef float  f32x4  __attribute__((ext_vector_type(4)));
typedef float  f32x2  __attribute__((ext_vector_type(2)));
typedef float  f32x16 __attribute__((ext_vector_type(16)));
typedef int    i32x8  __attribute__((ext_vector_type(8)));

__device__ __forceinline__ i32x8 mk8(uint4 lo, uint4 hi) {
  i32x8 v;
  v[0] = (int)lo.x; v[1] = (int)lo.y; v[2] = (int)lo.z; v[3] = (int)lo.w;
  v[4] = (int)hi.x; v[5] = (int)hi.y; v[6] = (int)hi.z; v[7] = (int)hi.w;
  return v;
}

// ------- merged weight prep: 4 transposes (fp8) + cat bias, 1 launch -------
__global__ __launch_bounds__(256) void prep_weights(
    const float* __restrict__ vp_w, const float* __restrict__ op_w,
    const float* __restrict__ so_w, const float* __restrict__ aw_w,
    const float* __restrict__ so_b, const float* __restrict__ aw_b,
    char* __restrict__ vp_w8, char* __restrict__ op_w8,
    char* __restrict__ cat_w8, float* __restrict__ cat_bp)
{
  const int b = blockIdx.x;
  if (b == 1536) {
    const int i = threadIdx.x;
#pragma unroll
    for (int it = 0; it < 2; ++it) {
      const int idx = i + it * 256;
      float v = 0.f;
      if (idx < 288) v = so_b[idx];
      else if (idx < 432) v = aw_b[idx - AW_OFF];
      cat_bp[idx] = v;
    }
    return;
  }
  const float* W; char* Wt; int Nsrc, rowoff; float scale;
  int lb;
  if (b < 576)       { W = vp_w; Wt = vp_w8;  Nsrc = 768; rowoff = 0;   scale = 1.f;  lb = b; }
  else if (b < 1152) { W = op_w; Wt = op_w8;  Nsrc = 768; rowoff = 0;   scale = 1.f;  lb = b - 576; }
  else if (b < 1368) { W = so_w; Wt = cat_w8; Nsrc = 288; rowoff = 0;   scale = WSCL; lb = b - 1152; }
  else               { W = aw_w; Wt = cat_w8; Nsrc = 144; rowoff = 288; scale = WSCL; lb = b - 1368; }

  __shared__ float t[32][33];
  const int k0 = (lb % 24) * 32;
  const int n0 = (lb / 24) * 32;
  const int tx = threadIdx.x & 31, ty = threadIdx.x >> 5;
#pragma unroll
  for (int i = ty; i < 32; i += 8) {
    const int n = n0 + tx;
    t[i][tx] = (n < Nsrc) ? W[(size_t)(k0 + i) * Nsrc + n] * scale : 0.f;
  }
  __syncthreads();
#pragma unroll
  for (int i = ty; i < 32; i += 8) {
    const int n = rowoff + n0 + i;
    uint32_t pk = __builtin_amdgcn_cvt_pk_fp8_f32(t[tx][i], 0.f, 0, false);
    Wt[(size_t)n * CDIM + k0 + tx] = (char)(pk & 0xff);
  }
}

// -------- LayerNorm, 1 wave/row, fp8 out; q and f merged in one launch -----
// blocks [0, MQ/4): query rows -> q_f8 ; [MQ/4, MQ/4+MF/4): feat -> f_f8.
__global__ __launch_bounds__(256) void ln_wave2(
    const float* __restrict__ xq, const float* __restrict__ wq,
    const float* __restrict__ bq, char* __restrict__ yq,
    const float* __restrict__ xf, const float* __restrict__ wf,
    const float* __restrict__ bf, char* __restrict__ yf)
{
  const float* x; const float* w; const float* b; char* y; int row;
  if (blockIdx.x < MQ / 4) {
    x = xq; w = wq; b = bq; y = yq;
    row = blockIdx.x * 4 + (threadIdx.x >> 6);
  } else {
    x = xf; w = wf; b = bf; y = yf;
    row = (blockIdx.x - MQ / 4) * 4 + (threadIdx.x >> 6);
  }
  const int lane = threadIdx.x & 63;
  const float4* xr = (const float4*)(x + (size_t)row * CDIM);
  float4 v[3];
  v[0] = xr[lane]; v[1] = xr[lane + 64]; v[2] = xr[lane + 128];
  float s1 = 0.f, s2 = 0.f;
#pragma unroll
  for (int i = 0; i < 3; ++i) {
    s1 += v[i].x + v[i].y + v[i].z + v[i].w;
    s2 += v[i].x*v[i].x + v[i].y*v[i].y + v[i].z*v[i].z + v[i].w*v[i].w;
  }
#pragma unroll
  for (int o = 32; o > 0; o >>= 1) { s1 += __shfl_xor(s1, o); s2 += __shfl_xor(s2, o); }
  const float mu = s1 * (1.f / CDIM);
  const float rs = rsqrtf(s2 * (1.f / CDIM) - mu * mu + 1e-6f);
#pragma unroll
  for (int i = 0; i < 3; ++i) {
    const float4 w4 = ((const float4*)w)[lane + i * 64];
    const float4 b4 = ((const float4*)b)[lane + i * 64];
    const float o0 = (v[i].x - mu) * rs * w4.x + b4.x;
    const float o1 = (v[i].y - mu) * rs * w4.y + b4.y;
    const float o2 = (v[i].z - mu) * rs * w4.z + b4.z;
    const float o3 = (v[i].w - mu) * rs * w4.w + b4.w;
    uint32_t pk = 0;
    pk = __builtin_amdgcn_cvt_pk_fp8_f32(o0, o1, pk, false);
    pk = __builtin_amdgcn_cvt_pk_fp8_f32(o2, o3, pk, true);
    ((uint32_t*)(y + (size_t)row * CDIM))[lane + i * 64] = pk;
  }
}

// ======== 128x128 MX-scaled fp8 GEMM: 32x32x64, 3-buf counted pipeline ======
// (R14-proven structure, reverted verbatim after R15/R16 B-from-global
// regressions: per-lane B reads shatter into ~32 cache lines/inst.)
// C = A[M][K](e4m3) * Wt[N][K](e4m3)^T. Unity e8m0 scales (0x7F) = exact fp8.
// 256 thr = 4 waves (2M x 2N), per-wave 64x64 = 2x2 of 32x32.
// LDS: 3 bufs x 16 KB = 48 KB -> 3 blocks/CU. One tile = 4 global_load_lds
// per wave (vmcnt +4). Prologue stages tiles 0,1 (8 outstanding) then
// vmcnt(4) => tile 0 landed. Iter t stages tile t+2; end-of-iter vmcnt(4)
// => tile t+1 landed. Tail: vmcnt(0) at t=nk-2, nothing at nk-1.
// Chunk swizzle p^(r&3). Operand frag: lane l = row (l&31), k = (l>>5)*32+e.
// C/D: col = lane&31, row = (reg&3)+8*(reg>>2)+4*(lane>>5) [verified R11].
// MODE 0: fp8 head-major value store; 1: f32 acc*oscale+bias; 2: resid+gamma.
template<int MODE>
__global__ __launch_bounds__(256, 3) void gemm_mx(
    const char* __restrict__ A, const char* __restrict__ Wt,
    const float* __restrict__ bias, void* __restrict__ Cout,
    int M, int N, int K, int nTN, float oscale,
    const float* __restrict__ resid, const float* __restrict__ gammav)
{
  __shared__ __align__(16) char lds[49152];   // 3 x 16 KiB

  int bid = blockIdx.x;
  const int nwg = gridDim.x;
  if ((nwg & 7) == 0) {                 // XCD-chunked swizzle (bijective)
    const int chunk = nwg >> 3;
    bid = (bid & 7) * chunk + (bid >> 3);
  }
  const int mt = bid / nTN, ntl = bid - mt * nTN;
  const int m0 = mt * 128, n0 = ntl * 128;
  const int tid  = threadIdx.x;
  const int lane = tid & 63, wid = tid >> 6;
  const int wm = wid >> 1, wn = wid & 1;          // 2x2 wave grid
  const int lr31 = lane & 31, lkb = lane >> 5;

  f32x16 acc[2][2] = {};

  auto stage = [&](int kt, int buf, int ab) {
    const char* srcM = ab ? Wt : A;
    const int base0 = ab ? n0 : m0;
    const int k0 = kt * 64;
    char* dst0 = lds + buf * 16384 + ab * 8192;
#pragma unroll
    for (int it = 0; it < 2; ++it) {
      const int i = it * 256 + tid;              // chunk 0..511
      const int r = i >> 2, p = i & 3;
      const int c = p ^ (r & 3);                 // source chunk (involution)
      const char* src = srcM + (size_t)(base0 + r) * K + k0 + c * 16;
      char* dst = dst0 + (it * 256 + wid * 64) * 16;   // + lane*16 by HW
      __builtin_amdgcn_global_load_lds(
          (const __attribute__((address_space(1))) uint32_t*)src,
          (__attribute__((address_space(3))) uint32_t*)dst, 16, 0, 0);
    }
  };
  auto rdop = [&](int buf, int ab, int row) -> i32x8 {
    const char* base = lds + buf * 16384 + ab * 8192 + row * 64;
    const int s = row & 3;
    const uint4 lo = *(const uint4*)(base + ((2 * lkb)     ^ s) * 16);
    const uint4 hi = *(const uint4*)(base + ((2 * lkb + 1) ^ s) * 16);
    return mk8(lo, hi);
  };

  const int nk = K >> 6;                          // 12 K-tiles
  // prologue: stage tiles 0,1 into bufs 0,1 (8 outstanding)
  stage(0, 0, 0); stage(0, 0, 1);
  stage(1, 1, 0); stage(1, 1, 1);
  asm volatile("s_waitcnt vmcnt(4)" ::: "memory");  // tile 0 landed
  __builtin_amdgcn_s_barrier();
  asm volatile("" ::: "memory");

  for (int t = 0; t < nk; ++t) {
    const int cur = t % 3;
    const i32x8 a0 = rdop(cur, 0, wm * 64 + lr31);
    const i32x8 a1 = rdop(cur, 0, wm * 64 + 32 + lr31);
    const i32x8 b0 = rdop(cur, 1, wn * 64 + lr31);
    const i32x8 b1 = rdop(cur, 1, wn * 64 + 32 + lr31);
    if (t + 2 < nk) { const int tb = (t + 2) % 3; stage(t + 2, tb, 0); stage(t + 2, tb, 1); }
    __builtin_amdgcn_s_setprio(1);
    acc[0][0] = __builtin_amdgcn_mfma_scale_f32_32x32x64_f8f6f4(
        a0, b0, acc[0][0], 0, 0, 0, 0x7F7F7F7F, 0, 0x7F7F7F7F);
    acc[0][1] = __builtin_amdgcn_mfma_scale_f32_32x32x64_f8f6f4(
        a0, b1, acc[0][1], 0, 0, 0, 0x7F7F7F7F, 0, 0x7F7F7F7F);
    acc[1][0] = __builtin_amdgcn_mfma_scale_f32_32x32x64_f8f6f4(
        a1, b0, acc[1][0], 0, 0, 0, 0x7F7F7F7F, 0, 0x7F7F7F7F);
    acc[1][1] = __builtin_amdgcn_mfma_scale_f32_32x32x64_f8f6f4(
        a1, b1, acc[1][1], 0, 0, 0, 0x7F7F7F7F, 0, 0x7F7F7F7F);
    __builtin_amdgcn_s_setprio(0);
    if (t + 2 < nk)      asm volatile("s_waitcnt vmcnt(4)" ::: "memory"); // t+1 landed
    else if (t + 1 < nk) asm volatile("s_waitcnt vmcnt(0)" ::: "memory"); // tail drain
    __builtin_amdgcn_s_barrier();
    asm volatile("" ::: "memory");
  }

  // ---- epilogue ----
  if constexpr (MODE == 0) {
    // fp8 head-major value store via per-wave LDS staging ([32][68] f32)
    const int head  = (n0 + wn * 64) >> 6;
    const int n_img = (unsigned)m0 / LIN;         // LIN%128==0: no crossing
    char* plane = (char*)Cout + ((size_t)(n_img * NHD + head) * LIN
                                 + (m0 - n_img * LIN)) * 64;
    float bcol[2];
#pragma unroll
    for (int nt2 = 0; nt2 < 2; ++nt2)
      bcol[nt2] = bias[n0 + wn * 64 + nt2 * 32 + lr31];
    float* my = (float*)(lds + wid * 8704);       // 4 x 8704 = 34816 <= 48K
#pragma unroll
    for (int mt2 = 0; mt2 < 2; ++mt2) {
#pragma unroll
      for (int nt2 = 0; nt2 < 2; ++nt2)
#pragma unroll
        for (int reg = 0; reg < 16; ++reg) {
          const int row = (reg & 3) + 8 * (reg >> 2) + 4 * lkb;
          my[row * 68 + nt2 * 32 + lr31] = acc[mt2][nt2][reg] + bcol[nt2];
        }
#pragma unroll
      for (int it = 0; it < 2; ++it) {
        const int idx = it * 64 + lane;           // 0..127
        const int row = idx >> 2, seg = idx & 3;
        const float* s = my + row * 68 + seg * 16;
        uint32_t w[4];
#pragma unroll
        for (int q = 0; q < 4; ++q) {
          uint32_t pk = 0;
          pk = __builtin_amdgcn_cvt_pk_fp8_f32(s[q*4+0], s[q*4+1], pk, false);
          pk = __builtin_amdgcn_cvt_pk_fp8_f32(s[q*4+2], s[q*4+3], pk, true);
          w[q] = pk;
        }
        char* orow = plane + (size_t)(wm * 64 + mt2 * 32 + row) * 64 + seg * 16;
        *(uint4*)orow = *(uint4*)w;
      }
    }
  } else {
#pragma unroll
    for (int nt2 = 0; nt2 < 2; ++nt2) {
      const int col = n0 + wn * 64 + nt2 * 32 + lr31;
      const float bcol = bias[col];
      float gcol = 0.f;
      if constexpr (MODE == 2) gcol = gammav[col];
#pragma unroll
      for (int mt2 = 0; mt2 < 2; ++mt2)
#pragma unroll
        for (int reg = 0; reg < 16; ++reg) {
          const int row = m0 + wm * 64 + mt2 * 32
                        + (reg & 3) + 8 * (reg >> 2) + 4 * lkb;
          const size_t o = (size_t)row * N + col;
          if constexpr (MODE == 1)
            ((float*)Cout)[o] = acc[mt2][nt2][reg] * oscale + bcol;
          else
            ((float*)Cout)[o] = resid[o] + gcol * (acc[mt2][nt2][reg] + bcol);
        }
    }
  }
}

// ---------------- softmax over 12 + pack sampling params --------------------
__global__ void softmax_pack(const float* __restrict__ raw,
                             const float* __restrict__ refp,
                             float4* __restrict__ params) {
  const int t = blockIdx.x * 256 + threadIdx.x;       // [0, MQ*NHD)
  const int h = t % NHD, nq = t / NHD;
  const float* p = raw + (size_t)nq * CAT_N + AW_OFF + h * 12;
  float v[12], m = -1e30f;
#pragma unroll
  for (int j = 0; j < 12; ++j) { v[j] = p[j]; m = fmaxf(m, v[j]); }
  float s = 0.f;
#pragma unroll
  for (int j = 0; j < 12; ++j) { v[j] = __expf(v[j] - m); s += v[j]; }
  const float inv = 1.f / s;
  const float* op = raw + (size_t)nq * CAT_N + h * 24;
  const float* rp = refp + (size_t)nq * (NLVL * 2);
  float4* out = params + (size_t)t * 12;
  const float Wf[3] = {128.f, 64.f, 32.f};
#pragma unroll
  for (int l = 0; l < NLVL; ++l) {
    const float rxw = rp[2 * l] * Wf[l] - 0.5f;
    const float ryw = rp[2 * l + 1] * Wf[l] - 0.5f;
#pragma unroll
    for (int pt = 0; pt < NPT; ++pt) {
      float4 o4;
      o4.x = rxw + op[(l * 4 + pt) * 2 + 0];
      o4.y = ryw + op[(l * 4 + pt) * 2 + 1];
      o4.z = v[l * 4 + pt] * inv;
      o4.w = 0.f;
      out[l * 4 + pt] = o4;
    }
  }
}

// ------------- deformable sampling: 16 channels/lane, fp8 ------------------
__global__ __launch_bounds__(256) void deform_grp16(
    const char* __restrict__ vbytes, const float4* __restrict__ params,
    char* __restrict__ samp)
{
  const int j = blockIdx.x;                   // 3072 blocks
  const int x = j & 7, k = j >> 3;            // k in [0,384)
  const int g = x + ((k >> 6) << 3);          // plane, pinned to XCD x
  const int i = k & 63;                       // block within group
  const int n = g / NHD, h = g - n * NHD;
  const int wid = threadIdx.x >> 6, lane = threadIdx.x & 63;
  const int qi = lane >> 2, ci = lane & 3;
  const int q  = i * 64 + wid * 16 + qi;      // [0, 4096)
  const int nq = n * LQ + q;
  const float4* __restrict__ pp = params + ((size_t)nq * NHD + h) * 12;
  const uint32_t base0 = (uint32_t)g * (uint32_t)(LIN * 64)
                       + ((uint32_t)ci << 4);

  float acc[16];
#pragma unroll
  for (int c = 0; c < 16; ++c) acc[c] = 0.f;

  const int      Wl[3]  = {128, 64, 32};
  const uint32_t STb[3] = {0u, 16384u * 64u, 20480u * 64u};

#pragma unroll
  for (int l = 0; l < NLVL; ++l) {
    const int W_ = Wl[l];
    const uint32_t base = base0 + STb[l];
#pragma unroll
    for (int p = 0; p < NPT; ++p) {
      const float4 pt = pp[l * 4 + p];
      const float fx = floorf(pt.x), fy = floorf(pt.y);
      const float tx = pt.x - fx,   ty = pt.y - fy;
      const int x0 = (int)fx, y0 = (int)fy;
      const int x1 = x0 + 1,  y1 = y0 + 1;
      const float wx0 = ((uint32_t)x0 < (uint32_t)W_) ? (1.f - tx) : 0.f;
      const float wx1 = ((uint32_t)x1 < (uint32_t)W_) ? tx : 0.f;
      const float wy0 = ((uint32_t)y0 < (uint32_t)W_) ? pt.z * (1.f - ty) : 0.f;
      const float wy1 = ((uint32_t)y1 < (uint32_t)W_) ? pt.z * ty : 0.f;
      const int xc0 = min(max(x0, 0), W_ - 1);
      const int xc1 = min(max(x1, 0), W_ - 1);
      const int yr0 = min(max(y0, 0), W_ - 1) * W_;
      const int yr1 = min(max(y1, 0), W_ - 1) * W_;
      const float cw[4] = {wy0 * wx0, wy0 * wx1, wy1 * wx0, wy1 * wx1};
      const uint4 G0 = *(const uint4*)(vbytes + base + (uint32_t)(yr0 + xc0) * 64u);
      const uint4 G1 = *(const uint4*)(vbytes + base + (uint32_t)(yr0 + xc1) * 64u);
      const uint4 G2 = *(const uint4*)(vbytes + base + (uint32_t)(yr1 + xc0) * 64u);
      const uint4 G3 = *(const uint4*)(vbytes + base + (uint32_t)(yr1 + xc1) * 64u);
      const uint4 GG[4] = {G0, G1, G2, G3};
#pragma unroll
      for (int cnr = 0; cnr < 4; ++cnr) {
        const uint32_t wds[4] = {GG[cnr].x, GG[cnr].y, GG[cnr].z, GG[cnr].w};
        const float wgt = cw[cnr];
#pragma unroll
        for (int wd = 0; wd < 4; ++wd) {
          f32x2 lo = __builtin_amdgcn_cvt_pk_f32_fp8(wds[wd], false);
          f32x2 hi = __builtin_amdgcn_cvt_pk_f32_fp8(wds[wd], true);
          acc[wd * 4 + 0] += lo[0] * wgt;
          acc[wd * 4 + 1] += lo[1] * wgt;
          acc[wd * 4 + 2] += hi[0] * wgt;
          acc[wd * 4 + 3] += hi[1] * wgt;
        }
      }
    }
  }

  uint32_t out[4];
#pragma unroll
  for (int wd = 0; wd < 4; ++wd) {
    uint32_t pk = 0;
    pk = __builtin_amdgcn_cvt_pk_fp8_f32(acc[wd*4+0], acc[wd*4+1], pk, false);
    pk = __builtin_amdgcn_cvt_pk_fp8_f32(acc[wd*4+2], acc[wd*4+3], pk, true);
    out[wd] = pk;
  }
  *(uint4*)(samp + (size_t)nq * CDIM + h * HDIM + ci * 16) = *(uint4*)out;
}

// ---------------- host ------------------------------------------------------
extern "C" void kernel_launch(void* const* d_in, const int* in_sizes, int n_in,
                              void* d_out, int out_size, void* d_ws, size_t ws_size,
                              hipStream_t stream) {
  const float* query = (const float*)d_in[0];
  const float* refp  = (const float*)d_in[1];
  const float* feat  = (const float*)d_in[2];
  const float* qn_w  = (const float*)d_in[3];
  const float* qn_b  = (const float*)d_in[4];
  const float* fn_w  = (const float*)d_in[5];
  const float* fn_b  = (const float*)d_in[6];
  const float* gamma = (const float*)d_in[7];
  const float* so_w  = (const float*)d_in[8];
  const float* so_b  = (const float*)d_in[9];
  const float* aw_w  = (const float*)d_in[10];
  const float* aw_b  = (const float*)d_in[11];
  const float* vp_w  = (const float*)d_in[12];
  const float* vp_b  = (const float*)d_in[13];
  const float* op_w  = (const float*)d_in[14];
  const float* op_b  = (const float*)d_in[15];

  char* ws = (char*)d_ws;
  size_t off = 0;
  auto alloc = [&](size_t bytes) {
    char* p = ws + off;
    off = (off + bytes + 255) & ~(size_t)255;
    return p;
  };
  char*   q_f8   = (char*)alloc((size_t)MQ * CDIM);
  char*   val_f8 = (char*)alloc((size_t)MF * CDIM);        // [48][LIN][64] e4m3
  char*   vp_w8  = (char*)alloc((size_t)CDIM * CDIM);
  char*   op_w8  = (char*)alloc((size_t)CDIM * CDIM);
  char*   cat_w8 = (char*)alloc((size_t)CAT_N * CDIM);     // x16 pre-scaled
  float*  cat_bp = (float*)alloc(CAT_N * 4);

  // region R: f_f8 (phase A) aliases the phase-B buffers
  const size_t r = off;
  char* f_f8 = ws + r;
  const size_t f_end = r + (size_t)MF * CDIM;
  size_t o2 = r;
  float*  raw     = (float*)(ws + o2);  o2 += (size_t)MQ * CAT_N * 4;
  float4* params  = (float4*)(ws + o2); o2 += (size_t)MQ * NHD * 12 * 16;
  char*   samp8   = (char*)(ws + o2);   o2 += (size_t)MQ * CDIM;
  const size_t need = (f_end > o2) ? f_end : o2;
  if (ws_size < need) return;   // ~180 MB required

  // 1) all weight prep in one launch (4 fp8 transposes + cat bias)
  prep_weights<<<1537, 256, 0, stream>>>(vp_w, op_w, so_w, aw_w, so_b, aw_b,
                                         vp_w8, op_w8, cat_w8, cat_bp);

  // 2) both layernorms (1 wave/row) -> fp8, single launch
  ln_wave2<<<(MQ + MF) / 4, 256, 0, stream>>>(query, qn_w, qn_b, q_f8,
                                              feat, fn_w, fn_b, f_f8);

  // 3) value = LN(feat) @ vp_w + vp_b   (MX 32x32x64, fp8 head-major out)
  gemm_mx<0><<<(MF / 128) * (CDIM / 128), 256, 0, stream>>>(
      f_f8, vp_w8, vp_b, val_f8, MF, CDIM, CDIM, CDIM / 128,
      1.f, nullptr, nullptr);

  // 4) fused so|aw GEMM (MX, f32 out, /16 descale)
  gemm_mx<1><<<(MQ / 128) * (CAT_N / 128), 256, 0, stream>>>(
      q_f8, cat_w8, cat_bp, raw, MQ, CAT_N, CDIM, CAT_N / 128,
      1.f / WSCL, nullptr, nullptr);

  // 5) softmax + pack {px,py,a} per (q,h,l,p)
  softmax_pack<<<(MQ * NHD) / 256, 256, 0, stream>>>(raw, refp, params);

  // 6) deformable sampling -> samp fp8 [MQ][768]  (16 ch/lane)
  deform_grp16<<<48 * 64, 256, 0, stream>>>(val_f8, params, samp8);

  // 7) out = query + gamma * (samp @ op_w + op_b)   (MX, fused f32 epilogue)
  gemm_mx<2><<<(MQ / 128) * (CDIM / 128), 256, 0, stream>>>(
      samp8, op_w8, op_b, (float*)d_out, MQ, CDIM, CDIM, CDIM / 128,
      1.f, query, gamma);
}

// Round 18
// 239.983 us; speedup vs baseline: 1.3444x; 1.1312x over previous
//
#include <hip/hip_runtime.h>
#include <hip/hip_bf16.h>
#include <stdint.h>

// ---------------- problem constants (fixed by setup_inputs) ----------------
#define NHD   12        // heads
#define NPT   4         // points
#define CDIM  768
#define HDIM  64
#define NLVL  3
#define LQ    4096
#define NB    4
#define LIN   21504     // 128*128 + 64*64 + 32*32
#define MQ    (NB*LQ)   // 16384 query rows
#define MF    (NB*LIN)  // 86016 feat rows
#define CAT_N 512       // fused so(288) | aw(144 real + pad)
#define AW_OFF 288
#define WSCL  16.f      // so/aw weight pre-scale (fp8 denormal avoidance)
#define PREP_NB 1537    // prep blocks inside the merged prep+ln launch

typedef float  f32x4  __attribute__((ext_vector_type(4)));
typedef float  f32x2  __attribute__((ext_vector_type(2)));
typedef float  f32x16 __attribute__((ext_vector_type(16)));
typedef int    i32x8  __attribute__((ext_vector_type(8)));

__device__ __forceinline__ i32x8 mk8(uint4 lo, uint4 hi) {
  i32x8 v;
  v[0] = (int)lo.x; v[1] = (int)lo.y; v[2] = (int)lo.z; v[3] = (int)lo.w;
  v[4] = (int)hi.x; v[5] = (int)hi.y; v[6] = (int)hi.z; v[7] = (int)hi.w;
  return v;
}

// ====== merged prep (4 fp8 transposes + cat bias) AND layernorms ============
// blocks [0,576): vp_w ; [576,1152): op_w ; [1152,1368): so_w (x16) ;
// [1368,1536): aw_w (x16) ; 1536: cat bias ;
// [PREP_NB, PREP_NB+MQ/4): LN(query)->q_f8 ; rest: LN(feat)->f_f8.
__global__ __launch_bounds__(256) void prep_and_ln(
    const float* __restrict__ vp_w, const float* __restrict__ op_w,
    const float* __restrict__ so_w, const float* __restrict__ aw_w,
    const float* __restrict__ so_b, const float* __restrict__ aw_b,
    char* __restrict__ vp_w8, char* __restrict__ op_w8,
    char* __restrict__ cat_w8, float* __restrict__ cat_bp,
    const float* __restrict__ xq, const float* __restrict__ wq,
    const float* __restrict__ bq, char* __restrict__ yq,
    const float* __restrict__ xf, const float* __restrict__ wf,
    const float* __restrict__ bf, char* __restrict__ yf)
{
  const int blk = blockIdx.x;
  if (blk >= PREP_NB) {
    // ---------------- LayerNorm, 1 wave/row, fp8 out ----------------
    const int lb = blk - PREP_NB;
    const float* x; const float* w; const float* b; char* y; int row;
    if (lb < MQ / 4) {
      x = xq; w = wq; b = bq; y = yq;
      row = lb * 4 + (threadIdx.x >> 6);
    } else {
      x = xf; w = wf; b = bf; y = yf;
      row = (lb - MQ / 4) * 4 + (threadIdx.x >> 6);
    }
    const int lane = threadIdx.x & 63;
    const float4* xr = (const float4*)(x + (size_t)row * CDIM);
    float4 v[3];
    v[0] = xr[lane]; v[1] = xr[lane + 64]; v[2] = xr[lane + 128];
    float s1 = 0.f, s2 = 0.f;
#pragma unroll
    for (int i = 0; i < 3; ++i) {
      s1 += v[i].x + v[i].y + v[i].z + v[i].w;
      s2 += v[i].x*v[i].x + v[i].y*v[i].y + v[i].z*v[i].z + v[i].w*v[i].w;
    }
#pragma unroll
    for (int o = 32; o > 0; o >>= 1) { s1 += __shfl_xor(s1, o); s2 += __shfl_xor(s2, o); }
    const float mu = s1 * (1.f / CDIM);
    const float rs = rsqrtf(s2 * (1.f / CDIM) - mu * mu + 1e-6f);
#pragma unroll
    for (int i = 0; i < 3; ++i) {
      const float4 w4 = ((const float4*)w)[lane + i * 64];
      const float4 b4 = ((const float4*)b)[lane + i * 64];
      const float o0 = (v[i].x - mu) * rs * w4.x + b4.x;
      const float o1 = (v[i].y - mu) * rs * w4.y + b4.y;
      const float o2 = (v[i].z - mu) * rs * w4.z + b4.z;
      const float o3 = (v[i].w - mu) * rs * w4.w + b4.w;
      uint32_t pk = 0;
      pk = __builtin_amdgcn_cvt_pk_fp8_f32(o0, o1, pk, false);
      pk = __builtin_amdgcn_cvt_pk_fp8_f32(o2, o3, pk, true);
      ((uint32_t*)(y + (size_t)row * CDIM))[lane + i * 64] = pk;
    }
    return;
  }
  // ---------------- weight prep ----------------
  const int b = blk;
  if (b == 1536) {
    const int i = threadIdx.x;
#pragma unroll
    for (int it = 0; it < 2; ++it) {
      const int idx = i + it * 256;
      float v = 0.f;
      if (idx < 288) v = so_b[idx];
      else if (idx < 432) v = aw_b[idx - AW_OFF];
      cat_bp[idx] = v;
    }
    return;
  }
  const float* W; char* Wt; int Nsrc, rowoff; float scale;
  int lb;
  if (b < 576)       { W = vp_w; Wt = vp_w8;  Nsrc = 768; rowoff = 0;   scale = 1.f;  lb = b; }
  else if (b < 1152) { W = op_w; Wt = op_w8;  Nsrc = 768; rowoff = 0;   scale = 1.f;  lb = b - 576; }
  else if (b < 1368) { W = so_w; Wt = cat_w8; Nsrc = 288; rowoff = 0;   scale = WSCL; lb = b - 1152; }
  else               { W = aw_w; Wt = cat_w8; Nsrc = 144; rowoff = 288; scale = WSCL; lb = b - 1368; }

  __shared__ float t[32][33];
  const int k0 = (lb % 24) * 32;
  const int n0 = (lb / 24) * 32;
  const int tx = threadIdx.x & 31, ty = threadIdx.x >> 5;
#pragma unroll
  for (int i = ty; i < 32; i += 8) {
    const int n = n0 + tx;
    t[i][tx] = (n < Nsrc) ? W[(size_t)(k0 + i) * Nsrc + n] * scale : 0.f;
  }
  __syncthreads();
#pragma unroll
  for (int i = ty; i < 32; i += 8) {
    const int n = rowoff + n0 + i;
    uint32_t pk = __builtin_amdgcn_cvt_pk_fp8_f32(t[tx][i], 0.f, 0, false);
    Wt[(size_t)n * CDIM + k0 + tx] = (char)(pk & 0xff);
  }
}

// ======== 128x128 MX-scaled fp8 GEMM: 32x32x64, 3-buf counted pipeline ======
// (R14-proven structure.) C = A[M][K](e4m3) * Wt[N][K](e4m3)^T; unity e8m0
// scales (0x7F) = exact fp8. 256 thr = 4 waves (2M x 2N), per-wave 64x64.
// LDS: 3 bufs x 16 KB -> 3 blocks/CU. One tile = 4 global_load_lds/wave.
// Prologue stages tiles 0,1 -> vmcnt(4) => tile 0 landed. Iter t stages
// t+2; end-of-iter vmcnt(4) => t+1 landed. Tail vmcnt(0) at nk-2.
// Chunk swizzle p^(r&3). Frag: lane l = row (l&31), k = (l>>5)*32+e.
// C/D: col = lane&31, row = (reg&3)+8*(reg>>2)+4*(lane>>5) [verified R11].
// MODE 0: fp8 head-major value store; 1: f32 acc*oscale+bias; 2: resid+gamma.
template<int MODE>
__global__ __launch_bounds__(256, 3) void gemm_mx(
    const char* __restrict__ A, const char* __restrict__ Wt,
    const float* __restrict__ bias, void* __restrict__ Cout,
    int M, int N, int K, int nTN, float oscale,
    const float* __restrict__ resid, const float* __restrict__ gammav)
{
  __shared__ __align__(16) char lds[49152];   // 3 x 16 KiB

  int bid = blockIdx.x;
  const int nwg = gridDim.x;
  if ((nwg & 7) == 0) {                 // XCD-chunked swizzle (bijective)
    const int chunk = nwg >> 3;
    bid = (bid & 7) * chunk + (bid >> 3);
  }
  const int mt = bid / nTN, ntl = bid - mt * nTN;
  const int m0 = mt * 128, n0 = ntl * 128;
  const int tid  = threadIdx.x;
  const int lane = tid & 63, wid = tid >> 6;
  const int wm = wid >> 1, wn = wid & 1;          // 2x2 wave grid
  const int lr31 = lane & 31, lkb = lane >> 5;

  f32x16 acc[2][2] = {};

  auto stage = [&](int kt, int buf, int ab) {
    const char* srcM = ab ? Wt : A;
    const int base0 = ab ? n0 : m0;
    const int k0 = kt * 64;
    char* dst0 = lds + buf * 16384 + ab * 8192;
#pragma unroll
    for (int it = 0; it < 2; ++it) {
      const int i = it * 256 + tid;              // chunk 0..511
      const int r = i >> 2, p = i & 3;
      const int c = p ^ (r & 3);                 // source chunk (involution)
      const char* src = srcM + (size_t)(base0 + r) * K + k0 + c * 16;
      char* dst = dst0 + (it * 256 + wid * 64) * 16;   // + lane*16 by HW
      __builtin_amdgcn_global_load_lds(
          (const __attribute__((address_space(1))) uint32_t*)src,
          (__attribute__((address_space(3))) uint32_t*)dst, 16, 0, 0);
    }
  };
  auto rdop = [&](int buf, int ab, int row) -> i32x8 {
    const char* base = lds + buf * 16384 + ab * 8192 + row * 64;
    const int s = row & 3;
    const uint4 lo = *(const uint4*)(base + ((2 * lkb)     ^ s) * 16);
    const uint4 hi = *(const uint4*)(base + ((2 * lkb + 1) ^ s) * 16);
    return mk8(lo, hi);
  };

  const int nk = K >> 6;                          // 12 K-tiles
  // prologue: stage tiles 0,1 into bufs 0,1 (8 outstanding)
  stage(0, 0, 0); stage(0, 0, 1);
  stage(1, 1, 0); stage(1, 1, 1);
  asm volatile("s_waitcnt vmcnt(4)" ::: "memory");  // tile 0 landed
  __builtin_amdgcn_s_barrier();
  asm volatile("" ::: "memory");

  for (int t = 0; t < nk; ++t) {
    const int cur = t % 3;
    const i32x8 a0 = rdop(cur, 0, wm * 64 + lr31);
    const i32x8 a1 = rdop(cur, 0, wm * 64 + 32 + lr31);
    const i32x8 b0 = rdop(cur, 1, wn * 64 + lr31);
    const i32x8 b1 = rdop(cur, 1, wn * 64 + 32 + lr31);
    if (t + 2 < nk) { const int tb = (t + 2) % 3; stage(t + 2, tb, 0); stage(t + 2, tb, 1); }
    __builtin_amdgcn_s_setprio(1);
    acc[0][0] = __builtin_amdgcn_mfma_scale_f32_32x32x64_f8f6f4(
        a0, b0, acc[0][0], 0, 0, 0, 0x7F7F7F7F, 0, 0x7F7F7F7F);
    acc[0][1] = __builtin_amdgcn_mfma_scale_f32_32x32x64_f8f6f4(
        a0, b1, acc[0][1], 0, 0, 0, 0x7F7F7F7F, 0, 0x7F7F7F7F);
    acc[1][0] = __builtin_amdgcn_mfma_scale_f32_32x32x64_f8f6f4(
        a1, b0, acc[1][0], 0, 0, 0, 0x7F7F7F7F, 0, 0x7F7F7F7F);
    acc[1][1] = __builtin_amdgcn_mfma_scale_f32_32x32x64_f8f6f4(
        a1, b1, acc[1][1], 0, 0, 0, 0x7F7F7F7F, 0, 0x7F7F7F7F);
    __builtin_amdgcn_s_setprio(0);
    if (t + 2 < nk)      asm volatile("s_waitcnt vmcnt(4)" ::: "memory"); // t+1 landed
    else if (t + 1 < nk) asm volatile("s_waitcnt vmcnt(0)" ::: "memory"); // tail drain
    __builtin_amdgcn_s_barrier();
    asm volatile("" ::: "memory");
  }

  // ---- epilogue ----
  if constexpr (MODE == 0) {
    // fp8 head-major value store via per-wave LDS staging ([32][68] f32)
    const int head  = (n0 + wn * 64) >> 6;
    const int n_img = (unsigned)m0 / LIN;         // LIN%128==0: no crossing
    char* plane = (char*)Cout + ((size_t)(n_img * NHD + head) * LIN
                                 + (m0 - n_img * LIN)) * 64;
    float bcol[2];
#pragma unroll
    for (int nt2 = 0; nt2 < 2; ++nt2)
      bcol[nt2] = bias[n0 + wn * 64 + nt2 * 32 + lr31];
    float* my = (float*)(lds + wid * 8704);       // 4 x 8704 = 34816 <= 48K
#pragma unroll
    for (int mt2 = 0; mt2 < 2; ++mt2) {
#pragma unroll
      for (int nt2 = 0; nt2 < 2; ++nt2)
#pragma unroll
        for (int reg = 0; reg < 16; ++reg) {
          const int row = (reg & 3) + 8 * (reg >> 2) + 4 * lkb;
          my[row * 68 + nt2 * 32 + lr31] = acc[mt2][nt2][reg] + bcol[nt2];
        }
#pragma unroll
      for (int it = 0; it < 2; ++it) {
        const int idx = it * 64 + lane;           // 0..127
        const int row = idx >> 2, seg = idx & 3;
        const float* s = my + row * 68 + seg * 16;
        uint32_t w[4];
#pragma unroll
        for (int q = 0; q < 4; ++q) {
          uint32_t pk = 0;
          pk = __builtin_amdgcn_cvt_pk_fp8_f32(s[q*4+0], s[q*4+1], pk, false);
          pk = __builtin_amdgcn_cvt_pk_fp8_f32(s[q*4+2], s[q*4+3], pk, true);
          w[q] = pk;
        }
        char* orow = plane + (size_t)(wm * 64 + mt2 * 32 + row) * 64 + seg * 16;
        *(uint4*)orow = *(uint4*)w;
      }
    }
  } else {
#pragma unroll
    for (int nt2 = 0; nt2 < 2; ++nt2) {
      const int col = n0 + wn * 64 + nt2 * 32 + lr31;
      const float bcol = bias[col];
      float gcol = 0.f;
      if constexpr (MODE == 2) gcol = gammav[col];
#pragma unroll
      for (int mt2 = 0; mt2 < 2; ++mt2)
#pragma unroll
        for (int reg = 0; reg < 16; ++reg) {
          const int row = m0 + wm * 64 + mt2 * 32
                        + (reg & 3) + 8 * (reg >> 2) + 4 * lkb;
          const size_t o = (size_t)row * N + col;
          if constexpr (MODE == 1)
            ((float*)Cout)[o] = acc[mt2][nt2][reg] * oscale + bcol;
          else
            ((float*)Cout)[o] = resid[o] + gcol * (acc[mt2][nt2][reg] + bcol);
        }
    }
  }
}

// ------- deformable sampling FUSED with softmax+param pack -----------------
// Block = plane g=(n,h), 64 queries. Phase 1: wave 0 (threads 0..63) computes
// softmax over 12 + {px,py,a} params for its query into LDS (reads raw's
// h-slice + refp, L2-hot). Phase 2: all 4 waves gather (16 ch/lane, fp8),
// params read from LDS (4-lane broadcast). Replaces softmax_pack kernel and
// the 37.7 MB params buffer round-trip.
__global__ __launch_bounds__(256) void deform_fused(
    const char* __restrict__ vbytes, const float* __restrict__ raw,
    const float* __restrict__ refp, char* __restrict__ samp)
{
  const int j = blockIdx.x;                   // 3072 blocks
  const int x = j & 7, k = j >> 3;            // k in [0,384)
  const int g = x + ((k >> 6) << 3);          // plane, pinned to XCD x
  const int i = k & 63;                       // block within group
  const int n = g / NHD, h = g - n * NHD;
  const int q0 = i * 64;

  __shared__ float4 pp_lds[64][12];

  if (threadIdx.x < 64) {
    const int nq = n * LQ + q0 + threadIdx.x;
    const float* praw = raw + (size_t)nq * CAT_N;
    float v[12], m = -1e30f;
#pragma unroll
    for (int jj = 0; jj < 12; ++jj) {
      v[jj] = praw[AW_OFF + h * 12 + jj];
      m = fmaxf(m, v[jj]);
    }
    float s = 0.f;
#pragma unroll
    for (int jj = 0; jj < 12; ++jj) { v[jj] = __expf(v[jj] - m); s += v[jj]; }
    const float inv = 1.f / s;
    const float* op = praw + h * 24;
    const float* rp = refp + (size_t)nq * (NLVL * 2);
    const float Wf[3] = {128.f, 64.f, 32.f};
#pragma unroll
    for (int l = 0; l < NLVL; ++l) {
      const float rxw = rp[2 * l] * Wf[l] - 0.5f;
      const float ryw = rp[2 * l + 1] * Wf[l] - 0.5f;
#pragma unroll
      for (int pt = 0; pt < NPT; ++pt) {
        float4 o4;
        o4.x = rxw + op[(l * 4 + pt) * 2 + 0];
        o4.y = ryw + op[(l * 4 + pt) * 2 + 1];
        o4.z = v[l * 4 + pt] * inv;
        o4.w = 0.f;
        pp_lds[threadIdx.x][l * 4 + pt] = o4;
      }
    }
  }
  __syncthreads();

  const int wid = threadIdx.x >> 6, lane = threadIdx.x & 63;
  const int qi = lane >> 2, ci = lane & 3;
  const int ql = wid * 16 + qi;               // query local 0..63
  const int nq = n * LQ + q0 + ql;
  const float4* __restrict__ pp = pp_lds[ql];
  const uint32_t base0 = (uint32_t)g * (uint32_t)(LIN * 64)
                       + ((uint32_t)ci << 4);

  float acc[16];
#pragma unroll
  for (int c = 0; c < 16; ++c) acc[c] = 0.f;

  const int      Wl[3]  = {128, 64, 32};
  const uint32_t STb[3] = {0u, 16384u * 64u, 20480u * 64u};

#pragma unroll
  for (int l = 0; l < NLVL; ++l) {
    const int W_ = Wl[l];
    const uint32_t base = base0 + STb[l];
#pragma unroll
    for (int p = 0; p < NPT; ++p) {
      const float4 pt = pp[l * 4 + p];
      const float fx = floorf(pt.x), fy = floorf(pt.y);
      const float tx = pt.x - fx,   ty = pt.y - fy;
      const int x0 = (int)fx, y0 = (int)fy;
      const int x1 = x0 + 1,  y1 = y0 + 1;
      const float wx0 = ((uint32_t)x0 < (uint32_t)W_) ? (1.f - tx) : 0.f;
      const float wx1 = ((uint32_t)x1 < (uint32_t)W_) ? tx : 0.f;
      const float wy0 = ((uint32_t)y0 < (uint32_t)W_) ? pt.z * (1.f - ty) : 0.f;
      const float wy1 = ((uint32_t)y1 < (uint32_t)W_) ? pt.z * ty : 0.f;
      const int xc0 = min(max(x0, 0), W_ - 1);
      const int xc1 = min(max(x1, 0), W_ - 1);
      const int yr0 = min(max(y0, 0), W_ - 1) * W_;
      const int yr1 = min(max(y1, 0), W_ - 1) * W_;
      const float cw[4] = {wy0 * wx0, wy0 * wx1, wy1 * wx0, wy1 * wx1};
      const uint4 G0 = *(const uint4*)(vbytes + base + (uint32_t)(yr0 + xc0) * 64u);
      const uint4 G1 = *(const uint4*)(vbytes + base + (uint32_t)(yr0 + xc1) * 64u);
      const uint4 G2 = *(const uint4*)(vbytes + base + (uint32_t)(yr1 + xc0) * 64u);
      const uint4 G3 = *(const uint4*)(vbytes + base + (uint32_t)(yr1 + xc1) * 64u);
      const uint4 GG[4] = {G0, G1, G2, G3};
#pragma unroll
      for (int cnr = 0; cnr < 4; ++cnr) {
        const uint32_t wds[4] = {GG[cnr].x, GG[cnr].y, GG[cnr].z, GG[cnr].w};
        const float wgt = cw[cnr];
#pragma unroll
        for (int wd = 0; wd < 4; ++wd) {
          f32x2 lo = __builtin_amdgcn_cvt_pk_f32_fp8(wds[wd], false);
          f32x2 hi = __builtin_amdgcn_cvt_pk_f32_fp8(wds[wd], true);
          acc[wd * 4 + 0] += lo[0] * wgt;
          acc[wd * 4 + 1] += lo[1] * wgt;
          acc[wd * 4 + 2] += hi[0] * wgt;
          acc[wd * 4 + 3] += hi[1] * wgt;
        }
      }
    }
  }

  uint32_t out[4];
#pragma unroll
  for (int wd = 0; wd < 4; ++wd) {
    uint32_t pk = 0;
    pk = __builtin_amdgcn_cvt_pk_fp8_f32(acc[wd*4+0], acc[wd*4+1], pk, false);
    pk = __builtin_amdgcn_cvt_pk_fp8_f32(acc[wd*4+2], acc[wd*4+3], pk, true);
    out[wd] = pk;
  }
  *(uint4*)(samp + (size_t)nq * CDIM + h * HDIM + ci * 16) = *(uint4*)out;
}

// ---------------- host ------------------------------------------------------
extern "C" void kernel_launch(void* const* d_in, const int* in_sizes, int n_in,
                              void* d_out, int out_size, void* d_ws, size_t ws_size,
                              hipStream_t stream) {
  const float* query = (const float*)d_in[0];
  const float* refp  = (const float*)d_in[1];
  const float* feat  = (const float*)d_in[2];
  const float* qn_w  = (const float*)d_in[3];
  const float* qn_b  = (const float*)d_in[4];
  const float* fn_w  = (const float*)d_in[5];
  const float* fn_b  = (const float*)d_in[6];
  const float* gamma = (const float*)d_in[7];
  const float* so_w  = (const float*)d_in[8];
  const float* so_b  = (const float*)d_in[9];
  const float* aw_w  = (const float*)d_in[10];
  const float* aw_b  = (const float*)d_in[11];
  const float* vp_w  = (const float*)d_in[12];
  const float* vp_b  = (const float*)d_in[13];
  const float* op_w  = (const float*)d_in[14];
  const float* op_b  = (const float*)d_in[15];

  char* ws = (char*)d_ws;
  size_t off = 0;
  auto alloc = [&](size_t bytes) {
    char* p = ws + off;
    off = (off + bytes + 255) & ~(size_t)255;
    return p;
  };
  char*   q_f8   = (char*)alloc((size_t)MQ * CDIM);
  char*   val_f8 = (char*)alloc((size_t)MF * CDIM);        // [48][LIN][64] e4m3
  char*   vp_w8  = (char*)alloc((size_t)CDIM * CDIM);
  char*   op_w8  = (char*)alloc((size_t)CDIM * CDIM);
  char*   cat_w8 = (char*)alloc((size_t)CAT_N * CDIM);     // x16 pre-scaled
  float*  cat_bp = (float*)alloc(CAT_N * 4);

  // region R: f_f8 (phase A) aliases the phase-B buffers
  const size_t r = off;
  char* f_f8 = ws + r;
  const size_t f_end = r + (size_t)MF * CDIM;
  size_t o2 = r;
  float*  raw     = (float*)(ws + o2);  o2 += (size_t)MQ * CAT_N * 4;
  char*   samp8   = (char*)(ws + o2);   o2 += (size_t)MQ * CDIM;
  const size_t need = (f_end > o2) ? f_end : o2;
  if (ws_size < need) return;   // ~180 MB required

  // 1+2) weight prep AND both layernorms, single launch
  prep_and_ln<<<PREP_NB + (MQ + MF) / 4, 256, 0, stream>>>(
      vp_w, op_w, so_w, aw_w, so_b, aw_b, vp_w8, op_w8, cat_w8, cat_bp,
      query, qn_w, qn_b, q_f8, feat, fn_w, fn_b, f_f8);

  // 3) value = LN(feat) @ vp_w + vp_b   (MX 32x32x64, fp8 head-major out)
  gemm_mx<0><<<(MF / 128) * (CDIM / 128), 256, 0, stream>>>(
      f_f8, vp_w8, vp_b, val_f8, MF, CDIM, CDIM, CDIM / 128,
      1.f, nullptr, nullptr);

  // 4) fused so|aw GEMM (MX, f32 out, /16 descale)
  gemm_mx<1><<<(MQ / 128) * (CAT_N / 128), 256, 0, stream>>>(
      q_f8, cat_w8, cat_bp, raw, MQ, CAT_N, CDIM, CAT_N / 128,
      1.f / WSCL, nullptr, nullptr);

  // 5+6) softmax+pack fused into deformable sampling -> samp fp8 [MQ][768]
  deform_fused<<<48 * 64, 256, 0, stream>>>(val_f8, raw, refp, samp8);

  // 7) out = query + gamma * (samp @ op_w + op_b)   (MX, fused f32 epilogue)
  gemm_mx<2><<<(MQ / 128) * (CDIM / 128), 256, 0, stream>>>(
      samp8, op_w8, op_b, (float*)d_out, MQ, CDIM, CDIM, CDIM / 128,
      1.f, query, gamma);
}

// Round 19
// 236.806 us; speedup vs baseline: 1.3625x; 1.0134x over previous
//
#include <hip/hip_runtime.h>
#include <hip/hip_bf16.h>
#include <stdint.h>

// ---------------- problem constants (fixed by setup_inputs) ----------------
#define NHD   12        // heads
#define NPT   4         // points
#define CDIM  768
#define HDIM  64
#define NLVL  3
#define LQ    4096
#define NB    4
#define LIN   21504     // 128*128 + 64*64 + 32*32
#define MQ    (NB*LQ)   // 16384 query rows
#define MF    (NB*LIN)  // 86016 feat rows
#define CAT_N 512       // fused so(288) | aw(144 real + pad)
#define AW_OFF 288
#define WSCL  16.f      // so/aw weight pre-scale (fp8 denormal avoidance)
#define PREP_NB 1537    // prep blocks inside the merged prep+ln launch
#define VAL_NWG ((MF/128)*(CDIM/128))   // 4032 value-GEMM blocks
#define CAT_NWG ((MQ/128)*(CAT_N/128))  // 512 cat-GEMM blocks

typedef float  f32x4  __attribute__((ext_vector_type(4)));
typedef float  f32x2  __attribute__((ext_vector_type(2)));
typedef float  f32x16 __attribute__((ext_vector_type(16)));
typedef int    i32x8  __attribute__((ext_vector_type(8)));

__device__ __forceinline__ i32x8 mk8(uint4 lo, uint4 hi) {
  i32x8 v;
  v[0] = (int)lo.x; v[1] = (int)lo.y; v[2] = (int)lo.z; v[3] = (int)lo.w;
  v[4] = (int)hi.x; v[5] = (int)hi.y; v[6] = (int)hi.z; v[7] = (int)hi.w;
  return v;
}

// ====== merged prep (4 fp8 transposes + cat bias) AND layernorms ============
__global__ __launch_bounds__(256) void prep_and_ln(
    const float* __restrict__ vp_w, const float* __restrict__ op_w,
    const float* __restrict__ so_w, const float* __restrict__ aw_w,
    const float* __restrict__ so_b, const float* __restrict__ aw_b,
    char* __restrict__ vp_w8, char* __restrict__ op_w8,
    char* __restrict__ cat_w8, float* __restrict__ cat_bp,
    const float* __restrict__ xq, const float* __restrict__ wq,
    const float* __restrict__ bq, char* __restrict__ yq,
    const float* __restrict__ xf, const float* __restrict__ wf,
    const float* __restrict__ bf, char* __restrict__ yf)
{
  const int blk = blockIdx.x;
  if (blk >= PREP_NB) {
    // ---------------- LayerNorm, 1 wave/row, fp8 out ----------------
    const int lb = blk - PREP_NB;
    const float* x; const float* w; const float* b; char* y; int row;
    if (lb < MQ / 4) {
      x = xq; w = wq; b = bq; y = yq;
      row = lb * 4 + (threadIdx.x >> 6);
    } else {
      x = xf; w = wf; b = bf; y = yf;
      row = (lb - MQ / 4) * 4 + (threadIdx.x >> 6);
    }
    const int lane = threadIdx.x & 63;
    const float4* xr = (const float4*)(x + (size_t)row * CDIM);
    float4 v[3];
    v[0] = xr[lane]; v[1] = xr[lane + 64]; v[2] = xr[lane + 128];
    float s1 = 0.f, s2 = 0.f;
#pragma unroll
    for (int i = 0; i < 3; ++i) {
      s1 += v[i].x + v[i].y + v[i].z + v[i].w;
      s2 += v[i].x*v[i].x + v[i].y*v[i].y + v[i].z*v[i].z + v[i].w*v[i].w;
    }
#pragma unroll
    for (int o = 32; o > 0; o >>= 1) { s1 += __shfl_xor(s1, o); s2 += __shfl_xor(s2, o); }
    const float mu = s1 * (1.f / CDIM);
    const float rs = rsqrtf(s2 * (1.f / CDIM) - mu * mu + 1e-6f);
#pragma unroll
    for (int i = 0; i < 3; ++i) {
      const float4 w4 = ((const float4*)w)[lane + i * 64];
      const float4 b4 = ((const float4*)b)[lane + i * 64];
      const float o0 = (v[i].x - mu) * rs * w4.x + b4.x;
      const float o1 = (v[i].y - mu) * rs * w4.y + b4.y;
      const float o2 = (v[i].z - mu) * rs * w4.z + b4.z;
      const float o3 = (v[i].w - mu) * rs * w4.w + b4.w;
      uint32_t pk = 0;
      pk = __builtin_amdgcn_cvt_pk_fp8_f32(o0, o1, pk, false);
      pk = __builtin_amdgcn_cvt_pk_fp8_f32(o2, o3, pk, true);
      ((uint32_t*)(y + (size_t)row * CDIM))[lane + i * 64] = pk;
    }
    return;
  }
  // ---------------- weight prep ----------------
  const int b = blk;
  if (b == 1536) {
    const int i = threadIdx.x;
#pragma unroll
    for (int it = 0; it < 2; ++it) {
      const int idx = i + it * 256;
      float v = 0.f;
      if (idx < 288) v = so_b[idx];
      else if (idx < 432) v = aw_b[idx - AW_OFF];
      cat_bp[idx] = v;
    }
    return;
  }
  const float* W; char* Wt; int Nsrc, rowoff; float scale;
  int lb;
  if (b < 576)       { W = vp_w; Wt = vp_w8;  Nsrc = 768; rowoff = 0;   scale = 1.f;  lb = b; }
  else if (b < 1152) { W = op_w; Wt = op_w8;  Nsrc = 768; rowoff = 0;   scale = 1.f;  lb = b - 576; }
  else if (b < 1368) { W = so_w; Wt = cat_w8; Nsrc = 288; rowoff = 0;   scale = WSCL; lb = b - 1152; }
  else               { W = aw_w; Wt = cat_w8; Nsrc = 144; rowoff = 288; scale = WSCL; lb = b - 1368; }

  __shared__ float t[32][33];
  const int k0 = (lb % 24) * 32;
  const int n0 = (lb / 24) * 32;
  const int tx = threadIdx.x & 31, ty = threadIdx.x >> 5;
#pragma unroll
  for (int i = ty; i < 32; i += 8) {
    const int n = n0 + tx;
    t[i][tx] = (n < Nsrc) ? W[(size_t)(k0 + i) * Nsrc + n] * scale : 0.f;
  }
  __syncthreads();
#pragma unroll
  for (int i = ty; i < 32; i += 8) {
    const int n = rowoff + n0 + i;
    uint32_t pk = __builtin_amdgcn_cvt_pk_fp8_f32(t[tx][i], 0.f, 0, false);
    Wt[(size_t)n * CDIM + k0 + tx] = (char)(pk & 0xff);
  }
}

// ==== dual GEMM launch: value (mode 0) + cat (mode 1), R14-proven K-loop ====
// Blocks [0, VAL_NWG): value = f_f8 @ vp_w8 -> fp8 head-major [g][LIN][64].
// Blocks [VAL_NWG, +CAT_NWG): cat = q_f8 @ cat_w8 -> f32 raw (acc/16 + bias).
// Inner loop identical for both (K=768, nk=12): 3 LDS bufs x 16 KB ->
// 3 blocks/CU; prologue stages tiles 0,1 -> vmcnt(4); iter t stages t+2,
// end-of-iter vmcnt(4); tail vmcnt(0) at nk-2. Chunk swizzle p^(r&3).
// Frag: lane l = row (l&31), k = (l>>5)*32+e. C/D: col = lane&31,
// row = (reg&3)+8*(reg>>2)+4*(lane>>5)  [verified R11].
__global__ __launch_bounds__(256, 3) void gemm_dual(
    const char* __restrict__ A0, const char* __restrict__ W0,
    const float* __restrict__ b0, char* __restrict__ C0,
    const char* __restrict__ A1, const char* __restrict__ W1,
    const float* __restrict__ b1, float* __restrict__ C1, float oscale1)
{
  __shared__ __align__(16) char lds[49152];   // 3 x 16 KiB

  int bid = blockIdx.x;
  int mode, nTN;
  const char* A; const char* Wt; const float* bias;
  if (bid < VAL_NWG) {
    mode = 0; nTN = CDIM / 128;
    A = A0; Wt = W0; bias = b0;
    const int chunk = VAL_NWG >> 3;               // 4032 % 8 == 0
    bid = (bid & 7) * chunk + (bid >> 3);
  } else {
    mode = 1; nTN = CAT_N / 128;
    A = A1; Wt = W1; bias = b1;
    bid -= VAL_NWG;
    const int chunk = CAT_NWG >> 3;               // 512 % 8 == 0
    bid = (bid & 7) * chunk + (bid >> 3);
  }
  const int mt = bid / nTN, ntl = bid - mt * nTN;
  const int m0 = mt * 128, n0 = ntl * 128;
  const int tid  = threadIdx.x;
  const int lane = tid & 63, wid = tid >> 6;
  const int wm = wid >> 1, wn = wid & 1;          // 2x2 wave grid
  const int lr31 = lane & 31, lkb = lane >> 5;
  const int K = CDIM;

  f32x16 acc[2][2] = {};

  auto stage = [&](int kt, int buf, int ab) {
    const char* srcM = ab ? Wt : A;
    const int base0 = ab ? n0 : m0;
    const int k0 = kt * 64;
    char* dst0 = lds + buf * 16384 + ab * 8192;
#pragma unroll
    for (int it = 0; it < 2; ++it) {
      const int i = it * 256 + tid;              // chunk 0..511
      const int r = i >> 2, p = i & 3;
      const int c = p ^ (r & 3);                 // source chunk (involution)
      const char* src = srcM + (size_t)(base0 + r) * K + k0 + c * 16;
      char* dst = dst0 + (it * 256 + wid * 64) * 16;   // + lane*16 by HW
      __builtin_amdgcn_global_load_lds(
          (const __attribute__((address_space(1))) uint32_t*)src,
          (__attribute__((address_space(3))) uint32_t*)dst, 16, 0, 0);
    }
  };
  auto rdop = [&](int buf, int ab, int row) -> i32x8 {
    const char* base = lds + buf * 16384 + ab * 8192 + row * 64;
    const int s = row & 3;
    const uint4 lo = *(const uint4*)(base + ((2 * lkb)     ^ s) * 16);
    const uint4 hi = *(const uint4*)(base + ((2 * lkb + 1) ^ s) * 16);
    return mk8(lo, hi);
  };

  const int nk = K >> 6;                          // 12 K-tiles
  stage(0, 0, 0); stage(0, 0, 1);
  stage(1, 1, 0); stage(1, 1, 1);
  asm volatile("s_waitcnt vmcnt(4)" ::: "memory");  // tile 0 landed
  __builtin_amdgcn_s_barrier();
  asm volatile("" ::: "memory");

  for (int t = 0; t < nk; ++t) {
    const int cur = t % 3;
    const i32x8 a0 = rdop(cur, 0, wm * 64 + lr31);
    const i32x8 a1 = rdop(cur, 0, wm * 64 + 32 + lr31);
    const i32x8 b0v = rdop(cur, 1, wn * 64 + lr31);
    const i32x8 b1v = rdop(cur, 1, wn * 64 + 32 + lr31);
    if (t + 2 < nk) { const int tb = (t + 2) % 3; stage(t + 2, tb, 0); stage(t + 2, tb, 1); }
    __builtin_amdgcn_s_setprio(1);
    acc[0][0] = __builtin_amdgcn_mfma_scale_f32_32x32x64_f8f6f4(
        a0, b0v, acc[0][0], 0, 0, 0, 0x7F7F7F7F, 0, 0x7F7F7F7F);
    acc[0][1] = __builtin_amdgcn_mfma_scale_f32_32x32x64_f8f6f4(
        a0, b1v, acc[0][1], 0, 0, 0, 0x7F7F7F7F, 0, 0x7F7F7F7F);
    acc[1][0] = __builtin_amdgcn_mfma_scale_f32_32x32x64_f8f6f4(
        a1, b0v, acc[1][0], 0, 0, 0, 0x7F7F7F7F, 0, 0x7F7F7F7F);
    acc[1][1] = __builtin_amdgcn_mfma_scale_f32_32x32x64_f8f6f4(
        a1, b1v, acc[1][1], 0, 0, 0, 0x7F7F7F7F, 0, 0x7F7F7F7F);
    __builtin_amdgcn_s_setprio(0);
    if (t + 2 < nk)      asm volatile("s_waitcnt vmcnt(4)" ::: "memory"); // t+1 landed
    else if (t + 1 < nk) asm volatile("s_waitcnt vmcnt(0)" ::: "memory"); // tail drain
    __builtin_amdgcn_s_barrier();
    asm volatile("" ::: "memory");
  }

  // ---- epilogue (block-uniform mode branch) ----
  if (mode == 0) {
    // fp8 head-major value store via per-wave LDS staging ([32][68] f32)
    const int head  = (n0 + wn * 64) >> 6;
    const int n_img = (unsigned)m0 / LIN;         // LIN%128==0: no crossing
    char* plane = C0 + ((size_t)(n_img * NHD + head) * LIN
                        + (m0 - n_img * LIN)) * 64;
    float bcol[2];
#pragma unroll
    for (int nt2 = 0; nt2 < 2; ++nt2)
      bcol[nt2] = bias[n0 + wn * 64 + nt2 * 32 + lr31];
    float* my = (float*)(lds + wid * 8704);       // 4 x 8704 = 34816 <= 48K
#pragma unroll
    for (int mt2 = 0; mt2 < 2; ++mt2) {
#pragma unroll
      for (int nt2 = 0; nt2 < 2; ++nt2)
#pragma unroll
        for (int reg = 0; reg < 16; ++reg) {
          const int row = (reg & 3) + 8 * (reg >> 2) + 4 * lkb;
          my[row * 68 + nt2 * 32 + lr31] = acc[mt2][nt2][reg] + bcol[nt2];
        }
#pragma unroll
      for (int it = 0; it < 2; ++it) {
        const int idx = it * 64 + lane;           // 0..127
        const int row = idx >> 2, seg = idx & 3;
        const float* s = my + row * 68 + seg * 16;
        uint32_t w[4];
#pragma unroll
        for (int q = 0; q < 4; ++q) {
          uint32_t pk = 0;
          pk = __builtin_amdgcn_cvt_pk_fp8_f32(s[q*4+0], s[q*4+1], pk, false);
          pk = __builtin_amdgcn_cvt_pk_fp8_f32(s[q*4+2], s[q*4+3], pk, true);
          w[q] = pk;
        }
        char* orow = plane + (size_t)(wm * 64 + mt2 * 32 + row) * 64 + seg * 16;
        *(uint4*)orow = *(uint4*)w;
      }
    }
  } else {
#pragma unroll
    for (int nt2 = 0; nt2 < 2; ++nt2) {
      const int col = n0 + wn * 64 + nt2 * 32 + lr31;
      const float bcol = bias[col];
#pragma unroll
      for (int mt2 = 0; mt2 < 2; ++mt2)
#pragma unroll
        for (int reg = 0; reg < 16; ++reg) {
          const int row = m0 + wm * 64 + mt2 * 32
                        + (reg & 3) + 8 * (reg >> 2) + 4 * lkb;
          C1[(size_t)row * CAT_N + col] = acc[mt2][nt2][reg] * oscale1 + bcol;
        }
    }
  }
}

// ===== out-proj GEMM (R14 structure, MODE 2: resid + gamma*(acc+bias)) =====
__global__ __launch_bounds__(256, 3) void gemm_op(
    const char* __restrict__ A, const char* __restrict__ Wt,
    const float* __restrict__ bias, float* __restrict__ Cout,
    const float* __restrict__ resid, const float* __restrict__ gammav)
{
  __shared__ __align__(16) char lds[49152];   // 3 x 16 KiB

  int bid = blockIdx.x;
  const int nwg = gridDim.x;
  { const int chunk = nwg >> 3; bid = (bid & 7) * chunk + (bid >> 3); }
  const int nTN = CDIM / 128;
  const int mt = bid / nTN, ntl = bid - mt * nTN;
  const int m0 = mt * 128, n0 = ntl * 128;
  const int tid  = threadIdx.x;
  const int lane = tid & 63, wid = tid >> 6;
  const int wm = wid >> 1, wn = wid & 1;
  const int lr31 = lane & 31, lkb = lane >> 5;
  const int K = CDIM;

  f32x16 acc[2][2] = {};

  auto stage = [&](int kt, int buf, int ab) {
    const char* srcM = ab ? Wt : A;
    const int base0 = ab ? n0 : m0;
    const int k0 = kt * 64;
    char* dst0 = lds + buf * 16384 + ab * 8192;
#pragma unroll
    for (int it = 0; it < 2; ++it) {
      const int i = it * 256 + tid;
      const int r = i >> 2, p = i & 3;
      const int c = p ^ (r & 3);
      const char* src = srcM + (size_t)(base0 + r) * K + k0 + c * 16;
      char* dst = dst0 + (it * 256 + wid * 64) * 16;
      __builtin_amdgcn_global_load_lds(
          (const __attribute__((address_space(1))) uint32_t*)src,
          (__attribute__((address_space(3))) uint32_t*)dst, 16, 0, 0);
    }
  };
  auto rdop = [&](int buf, int ab, int row) -> i32x8 {
    const char* base = lds + buf * 16384 + ab * 8192 + row * 64;
    const int s = row & 3;
    const uint4 lo = *(const uint4*)(base + ((2 * lkb)     ^ s) * 16);
    const uint4 hi = *(const uint4*)(base + ((2 * lkb + 1) ^ s) * 16);
    return mk8(lo, hi);
  };

  const int nk = K >> 6;
  stage(0, 0, 0); stage(0, 0, 1);
  stage(1, 1, 0); stage(1, 1, 1);
  asm volatile("s_waitcnt vmcnt(4)" ::: "memory");
  __builtin_amdgcn_s_barrier();
  asm volatile("" ::: "memory");

  for (int t = 0; t < nk; ++t) {
    const int cur = t % 3;
    const i32x8 a0 = rdop(cur, 0, wm * 64 + lr31);
    const i32x8 a1 = rdop(cur, 0, wm * 64 + 32 + lr31);
    const i32x8 b0 = rdop(cur, 1, wn * 64 + lr31);
    const i32x8 b1 = rdop(cur, 1, wn * 64 + 32 + lr31);
    if (t + 2 < nk) { const int tb = (t + 2) % 3; stage(t + 2, tb, 0); stage(t + 2, tb, 1); }
    __builtin_amdgcn_s_setprio(1);
    acc[0][0] = __builtin_amdgcn_mfma_scale_f32_32x32x64_f8f6f4(
        a0, b0, acc[0][0], 0, 0, 0, 0x7F7F7F7F, 0, 0x7F7F7F7F);
    acc[0][1] = __builtin_amdgcn_mfma_scale_f32_32x32x64_f8f6f4(
        a0, b1, acc[0][1], 0, 0, 0, 0x7F7F7F7F, 0, 0x7F7F7F7F);
    acc[1][0] = __builtin_amdgcn_mfma_scale_f32_32x32x64_f8f6f4(
        a1, b0, acc[1][0], 0, 0, 0, 0x7F7F7F7F, 0, 0x7F7F7F7F);
    acc[1][1] = __builtin_amdgcn_mfma_scale_f32_32x32x64_f8f6f4(
        a1, b1, acc[1][1], 0, 0, 0, 0x7F7F7F7F, 0, 0x7F7F7F7F);
    __builtin_amdgcn_s_setprio(0);
    if (t + 2 < nk)      asm volatile("s_waitcnt vmcnt(4)" ::: "memory");
    else if (t + 1 < nk) asm volatile("s_waitcnt vmcnt(0)" ::: "memory");
    __builtin_amdgcn_s_barrier();
    asm volatile("" ::: "memory");
  }

#pragma unroll
  for (int nt2 = 0; nt2 < 2; ++nt2) {
    const int col = n0 + wn * 64 + nt2 * 32 + lr31;
    const float bcol = bias[col];
    const float gcol = gammav[col];
#pragma unroll
    for (int mt2 = 0; mt2 < 2; ++mt2)
#pragma unroll
      for (int reg = 0; reg < 16; ++reg) {
        const int row = m0 + wm * 64 + mt2 * 32
                      + (reg & 3) + 8 * (reg >> 2) + 4 * lkb;
        const size_t o = (size_t)row * CDIM + col;
        Cout[o] = resid[o] + gcol * (acc[mt2][nt2][reg] + bcol);
      }
  }
}

// ------- deformable sampling FUSED with softmax+param pack -----------------
// Block = plane g=(n,h), 64 queries. Phase 1 (ALL 256 threads, 4 per query):
// thread (ql = t>>2, s = t&3) handles 3 of 12 logits; quad shfl_xor reduce
// for max/sum; writes 3 params into LDS. Phase 2: gather (16 ch/lane, fp8).
__global__ __launch_bounds__(256) void deform_fused(
    const char* __restrict__ vbytes, const float* __restrict__ raw,
    const float* __restrict__ refp, char* __restrict__ samp)
{
  const int j = blockIdx.x;                   // 3072 blocks
  const int x = j & 7, k = j >> 3;            // k in [0,384)
  const int g = x + ((k >> 6) << 3);          // plane, pinned to XCD x
  const int i = k & 63;                       // block within group
  const int n = g / NHD, h = g - n * NHD;
  const int q0 = i * 64;

  __shared__ float4 pp_lds[64][12];

  {
    const int ql = threadIdx.x >> 2;          // 0..63
    const int s  = threadIdx.x & 3;           // 0..3 -> logits s*3..s*3+2
    const int nq = n * LQ + q0 + ql;
    const float* praw = raw + (size_t)nq * CAT_N;
    float v[3], m = -1e30f;
#pragma unroll
    for (int jj = 0; jj < 3; ++jj) {
      v[jj] = praw[AW_OFF + h * 12 + s * 3 + jj];
      m = fmaxf(m, v[jj]);
    }
    m = fmaxf(m, __shfl_xor(m, 1));
    m = fmaxf(m, __shfl_xor(m, 2));
    float sum = 0.f;
#pragma unroll
    for (int jj = 0; jj < 3; ++jj) { v[jj] = __expf(v[jj] - m); sum += v[jj]; }
    sum += __shfl_xor(sum, 1);
    sum += __shfl_xor(sum, 2);
    const float inv = 1.f / sum;
    const float* op = praw + h * 24;
    const float* rp = refp + (size_t)nq * (NLVL * 2);
#pragma unroll
    for (int jj = 0; jj < 3; ++jj) {
      const int jd = s * 3 + jj;
      const int l = jd >> 2;
      const float Wf = (float)(128 >> l);
      float4 o4;
      o4.x = rp[2 * l] * Wf - 0.5f + op[jd * 2 + 0];
      o4.y = rp[2 * l + 1] * Wf - 0.5f + op[jd * 2 + 1];
      o4.z = v[jj] * inv;
      o4.w = 0.f;
      pp_lds[ql][jd] = o4;
    }
  }
  __syncthreads();

  const int wid = threadIdx.x >> 6, lane = threadIdx.x & 63;
  const int qi = lane >> 2, ci = lane & 3;
  const int ql = wid * 16 + qi;               // query local 0..63
  const int nq = n * LQ + q0 + ql;
  const float4* __restrict__ pp = pp_lds[ql];
  const uint32_t base0 = (uint32_t)g * (uint32_t)(LIN * 64)
                       + ((uint32_t)ci << 4);

  float acc[16];
#pragma unroll
  for (int c = 0; c < 16; ++c) acc[c] = 0.f;

  const int      Wl[3]  = {128, 64, 32};
  const uint32_t STb[3] = {0u, 16384u * 64u, 20480u * 64u};

#pragma unroll
  for (int l = 0; l < NLVL; ++l) {
    const int W_ = Wl[l];
    const uint32_t base = base0 + STb[l];
#pragma unroll
    for (int p = 0; p < NPT; ++p) {
      const float4 pt = pp[l * 4 + p];
      const float fx = floorf(pt.x), fy = floorf(pt.y);
      const float tx = pt.x - fx,   ty = pt.y - fy;
      const int x0 = (int)fx, y0 = (int)fy;
      const int x1 = x0 + 1,  y1 = y0 + 1;
      const float wx0 = ((uint32_t)x0 < (uint32_t)W_) ? (1.f - tx) : 0.f;
      const float wx1 = ((uint32_t)x1 < (uint32_t)W_) ? tx : 0.f;
      const float wy0 = ((uint32_t)y0 < (uint32_t)W_) ? pt.z * (1.f - ty) : 0.f;
      const float wy1 = ((uint32_t)y1 < (uint32_t)W_) ? pt.z * ty : 0.f;
      const int xc0 = min(max(x0, 0), W_ - 1);
      const int xc1 = min(max(x1, 0), W_ - 1);
      const int yr0 = min(max(y0, 0), W_ - 1) * W_;
      const int yr1 = min(max(y1, 0), W_ - 1) * W_;
      const float cw[4] = {wy0 * wx0, wy0 * wx1, wy1 * wx0, wy1 * wx1};
      const uint4 G0 = *(const uint4*)(vbytes + base + (uint32_t)(yr0 + xc0) * 64u);
      const uint4 G1 = *(const uint4*)(vbytes + base + (uint32_t)(yr0 + xc1) * 64u);
      const uint4 G2 = *(const uint4*)(vbytes + base + (uint32_t)(yr1 + xc0) * 64u);
      const uint4 G3 = *(const uint4*)(vbytes + base + (uint32_t)(yr1 + xc1) * 64u);
      const uint4 GG[4] = {G0, G1, G2, G3};
#pragma unroll
      for (int cnr = 0; cnr < 4; ++cnr) {
        const uint32_t wds[4] = {GG[cnr].x, GG[cnr].y, GG[cnr].z, GG[cnr].w};
        const float wgt = cw[cnr];
#pragma unroll
        for (int wd = 0; wd < 4; ++wd) {
          f32x2 lo = __builtin_amdgcn_cvt_pk_f32_fp8(wds[wd], false);
          f32x2 hi = __builtin_amdgcn_cvt_pk_f32_fp8(wds[wd], true);
          acc[wd * 4 + 0] += lo[0] * wgt;
          acc[wd * 4 + 1] += lo[1] * wgt;
          acc[wd * 4 + 2] += hi[0] * wgt;
          acc[wd * 4 + 3] += hi[1] * wgt;
        }
      }
    }
  }

  uint32_t out[4];
#pragma unroll
  for (int wd = 0; wd < 4; ++wd) {
    uint32_t pk = 0;
    pk = __builtin_amdgcn_cvt_pk_fp8_f32(acc[wd*4+0], acc[wd*4+1], pk, false);
    pk = __builtin_amdgcn_cvt_pk_fp8_f32(acc[wd*4+2], acc[wd*4+3], pk, true);
    out[wd] = pk;
  }
  *(uint4*)(samp + (size_t)nq * CDIM + h * HDIM + ci * 16) = *(uint4*)out;
}

// ---------------- host ------------------------------------------------------
extern "C" void kernel_launch(void* const* d_in, const int* in_sizes, int n_in,
                              void* d_out, int out_size, void* d_ws, size_t ws_size,
                              hipStream_t stream) {
  const float* query = (const float*)d_in[0];
  const float* refp  = (const float*)d_in[1];
  const float* feat  = (const float*)d_in[2];
  const float* qn_w  = (const float*)d_in[3];
  const float* qn_b  = (const float*)d_in[4];
  const float* fn_w  = (const float*)d_in[5];
  const float* fn_b  = (const float*)d_in[6];
  const float* gamma = (const float*)d_in[7];
  const float* so_w  = (const float*)d_in[8];
  const float* so_b  = (const float*)d_in[9];
  const float* aw_w  = (const float*)d_in[10];
  const float* aw_b  = (const float*)d_in[11];
  const float* vp_w  = (const float*)d_in[12];
  const float* vp_b  = (const float*)d_in[13];
  const float* op_w  = (const float*)d_in[14];
  const float* op_b  = (const float*)d_in[15];

  char* ws = (char*)d_ws;
  size_t off = 0;
  auto alloc = [&](size_t bytes) {
    char* p = ws + off;
    off = (off + bytes + 255) & ~(size_t)255;
    return p;
  };
  char*   q_f8   = (char*)alloc((size_t)MQ * CDIM);
  char*   val_f8 = (char*)alloc((size_t)MF * CDIM);        // [48][LIN][64] e4m3
  char*   vp_w8  = (char*)alloc((size_t)CDIM * CDIM);
  char*   op_w8  = (char*)alloc((size_t)CDIM * CDIM);
  char*   cat_w8 = (char*)alloc((size_t)CAT_N * CDIM);     // x16 pre-scaled
  float*  cat_bp = (float*)alloc(CAT_N * 4);

  // region R: f_f8 (phase A) aliases the phase-B buffers
  const size_t r = off;
  char* f_f8 = ws + r;
  const size_t f_end = r + (size_t)MF * CDIM;
  size_t o2 = r;
  float*  raw     = (float*)(ws + o2);  o2 += (size_t)MQ * CAT_N * 4;
  char*   samp8   = (char*)(ws + o2);   o2 += (size_t)MQ * CDIM;
  const size_t need = (f_end > o2) ? f_end : o2;
  if (ws_size < need) return;   // ~180 MB required

  // 1) weight prep AND both layernorms, single launch
  prep_and_ln<<<PREP_NB + (MQ + MF) / 4, 256, 0, stream>>>(
      vp_w, op_w, so_w, aw_w, so_b, aw_b, vp_w8, op_w8, cat_w8, cat_bp,
      query, qn_w, qn_b, q_f8, feat, fn_w, fn_b, f_f8);

  // 2) value GEMM + cat GEMM in ONE launch (cat fills value's tail round)
  gemm_dual<<<VAL_NWG + CAT_NWG, 256, 0, stream>>>(
      f_f8, vp_w8, vp_b, val_f8,
      q_f8, cat_w8, cat_bp, raw, 1.f / WSCL);

  // 3) softmax+pack fused into deformable sampling -> samp fp8 [MQ][768]
  deform_fused<<<48 * 64, 256, 0, stream>>>(val_f8, raw, refp, samp8);

  // 4) out = query + gamma * (samp @ op_w + op_b)
  gemm_op<<<(MQ / 128) * (CDIM / 128), 256, 0, stream>>>(
      samp8, op_w8, op_b, (float*)d_out, query, gamma);
}